// Round 6
// baseline (3801.120 us; speedup 1.0000x reference)
//
#include <hip/hip_runtime.h>

// ---------------------------------------------------------------------------
// Problem constants
// ---------------------------------------------------------------------------
static constexpr int LSEQ = 512;   // timesteps
static constexpr int NB   = 256;   // batch
static constexpr int CIN  = 256;   // input dim
static constexpr int HD   = 512;   // hidden dim
static constexpr int G3   = 1536;  // 3*HD
static constexpr int NOUT = 256;   // output dim

typedef __attribute__((ext_vector_type(8))) short bf16x8;
typedef __attribute__((ext_vector_type(4))) float f32x4;
typedef __attribute__((ext_vector_type(8))) unsigned short u16x8;
typedef __attribute__((ext_vector_type(4))) unsigned u32x4;

#define DEVI __device__ __forceinline__

DEVI float b2f(unsigned short h) { return __uint_as_float(((unsigned)h) << 16); }
DEVI unsigned short f2b(float x) {
    unsigned u = __float_as_uint(x);
    return (unsigned short)((u + 0x7FFFu + ((u >> 16) & 1u)) >> 16);
}

// Device-coherent dword access (LLC coherence point; safe across XCDs).
DEVI unsigned cload(const unsigned* p) {
    return __hip_atomic_load(p, __ATOMIC_RELAXED, __HIP_MEMORY_SCOPE_AGENT);
}
DEVI void cstore(unsigned* p, unsigned v) {
    __hip_atomic_store(p, v, __ATOMIC_RELAXED, __HIP_MEMORY_SCOPE_AGENT);
}

// exp-based tanh: no libm branches (tanhf was ~2x the gate-math cost).
// Clamp keeps e^{-2x} finite; |x|>=10 -> tanh == +-1 to bf16 precision.
DEVI float fast_tanh(float x) {
    x = fminf(10.f, fmaxf(-10.f, x));
    float e = __expf(-2.f * x);
    return (1.f - e) / (1.f + e);
}

// 4x coherent 16B loads (LLC), one waitcnt. sched_barrier guards against the
// compiler hoisting register-only consumers past the inline-asm waitcnt.
DEVI void cload4x4(const unsigned* p0, const unsigned* p1,
                   const unsigned* p2, const unsigned* p3,
                   u32x4& r0, u32x4& r1, u32x4& r2, u32x4& r3) {
    asm volatile(
        "global_load_dwordx4 %0, %4, off sc0 sc1\n\t"
        "global_load_dwordx4 %1, %5, off sc0 sc1\n\t"
        "global_load_dwordx4 %2, %6, off sc0 sc1\n\t"
        "global_load_dwordx4 %3, %7, off sc0 sc1\n\t"
        "s_waitcnt vmcnt(0)"
        : "=&v"(r0), "=&v"(r1), "=&v"(r2), "=&v"(r3)
        : "v"(p0), "v"(p1), "v"(p2), "v"(p3)
        : "memory");
    __builtin_amdgcn_sched_barrier(0);
}

// ---------------------------------------------------------------------------
// Float-dtype detection: if data is f32, the low u16 of each float is random
// mantissa bits -> "bf16" exponent field >= 0xC0 (|v|>=2^65) ~25% of the time.
// ---------------------------------------------------------------------------
__global__ void detect_fdt(const unsigned short* __restrict__ x, int nHalf,
                           unsigned* __restrict__ fdt) {
    __shared__ unsigned big;
    if (threadIdx.x == 0) big = 0;
    __syncthreads();
    for (int i = threadIdx.x; i < nHalf; i += 256) {
        unsigned e = (x[i] >> 7) & 0xFFu;
        if (e >= 0xC0u) atomicOr(&big, 1u);
    }
    __syncthreads();
    if (threadIdx.x == 0) *fdt = big ? 1u : 0u;
}

// Cast a float tensor (f32 or bf16 per *fdt) to a bf16 staging buffer.
__global__ void cast_bf16(const void* __restrict__ src, long srcOff,
                          unsigned short* __restrict__ dst, long n,
                          const unsigned* __restrict__ fdt) {
    long i = (long)blockIdx.x * 256 + threadIdx.x;
    long stride = (long)gridDim.x * 256;
    if (*fdt) {
        const float* s = (const float*)src + srcOff;
        for (; i < n; i += stride) dst[i] = f2b(s[i]);
    } else {
        const unsigned short* s = (const unsigned short*)src + srcOff;
        for (; i < n; i += stride) dst[i] = s[i];
    }
}

// ---------------------------------------------------------------------------
// done-mask dtype detection (bool/int8 vs int32 vs bf16 vs f32)
// ---------------------------------------------------------------------------
__global__ void detect_done(const unsigned char* __restrict__ d, int elems,
                            unsigned* __restrict__ flag) {
    __shared__ unsigned bad[4];
    int tid = threadIdx.x;
    if (tid < 4) bad[tid] = 0;
    __syncthreads();
    int nInt = elems >> 2;
    const unsigned* di = (const unsigned*)d;
    for (int i = tid; i < nInt; i += 256) {
        unsigned v = di[i];
        if (v > 1u) atomicOr(&bad[0], 1u);
        if (v != 0u && v != 0x3F800000u) atomicOr(&bad[1], 1u);
    }
    int nHalf = elems >> 1;
    const unsigned short* dh = (const unsigned short*)d;
    for (int i = tid; i < nHalf; i += 256) {
        unsigned short h = dh[i];
        if (h != 0 && h != 0x3F80) atomicOr(&bad[2], 1u);
    }
    __syncthreads();
    if (tid == 0) {
        unsigned f;
        if (!bad[0]) f = 0u;       // int32 0/1
        else if (!bad[1]) f = 3u;  // float32
        else if (!bad[2]) f = 2u;  // bf16
        else f = 1u;               // bytes (bool / int8)
        *flag = f;
    }
}

__global__ void expand_done(const void* __restrict__ d, const unsigned* __restrict__ flag,
                            float* __restrict__ keep, int elems) {
    int i = blockIdx.x * 256 + threadIdx.x;
    if (i >= elems) return;
    unsigned f = *flag;
    float v;
    if (f == 0u)      v = (float)((const int*)d)[i];
    else if (f == 1u) v = (float)((const unsigned char*)d)[i];
    else if (f == 2u) v = b2f(((const unsigned short*)d)[i]);
    else              v = ((const float*)d)[i];
    keep[i] = 1.f - v;
}

// ---------------------------------------------------------------------------
// NT GEMM: C[M,N] = A[M,K] @ B[N,K]^T + bias, bf16 in, f32 accum.
// m97-style: 128x128 tile, BK=64, 4 waves, 16x16x32 MFMA, global_load_lds.
// ---------------------------------------------------------------------------
__global__ __launch_bounds__(256) void gemm_nt(
    const unsigned short* __restrict__ A, const unsigned short* __restrict__ B,
    const unsigned short* __restrict__ bias, unsigned short* __restrict__ C,
    float* __restrict__ Cf, const unsigned* __restrict__ fdt,
    int M, int N, int K) {
    __shared__ unsigned short sm[16384];  // A: [0,8192), B: [8192,16384)
    const int tid = threadIdx.x;
    const int l = tid & 63, w = tid >> 6;
    const int lr = l & 15, lq = l >> 4;
    const int wr = w >> 1, wc = w & 1;
    const long rowBase = (long)blockIdx.y * 128;
    const long colBase = (long)blockIdx.x * 128;

    int qrow[4], qc8[4];
#pragma unroll
    for (int i = 0; i < 4; i++) {
        int q = (i * 4 + w) * 64 + l;  // 16B-chunk id within the 128x64 tile
        qrow[i] = q >> 3;
        qc8[i] = (q & 7) * 8;
    }

    f32x4 acc[4][4] = {};

    for (int k0 = 0; k0 < K; k0 += 64) {
#pragma unroll
        for (int i = 0; i < 4; i++) {
            const unsigned short* sA = A + (rowBase + qrow[i]) * K + k0 + qc8[i];
            const unsigned short* sB = B + (colBase + qrow[i]) * K + k0 + qc8[i];
            __builtin_amdgcn_global_load_lds(
                (const __attribute__((address_space(1))) void*)sA,
                (__attribute__((address_space(3))) void*)(sm + (i * 4 + w) * 512), 16, 0, 0);
            __builtin_amdgcn_global_load_lds(
                (const __attribute__((address_space(1))) void*)sB,
                (__attribute__((address_space(3))) void*)(sm + 8192 + (i * 4 + w) * 512), 16, 0, 0);
        }
        __syncthreads();
#pragma unroll
        for (int ks = 0; ks < 2; ks++) {
            bf16x8 af[4], bfr[4];
#pragma unroll
            for (int mi = 0; mi < 4; mi++)
                af[mi] = *(const bf16x8*)&sm[(wr * 64 + mi * 16 + lr) * 64 + ks * 32 + lq * 8];
#pragma unroll
            for (int ni = 0; ni < 4; ni++)
                bfr[ni] = *(const bf16x8*)&sm[8192 + (wc * 64 + ni * 16 + lr) * 64 + ks * 32 + lq * 8];
#pragma unroll
            for (int mi = 0; mi < 4; mi++)
#pragma unroll
                for (int ni = 0; ni < 4; ni++)
                    acc[mi][ni] = __builtin_amdgcn_mfma_f32_16x16x32_bf16(
                        af[mi], bfr[ni], acc[mi][ni], 0, 0, 0);
        }
        __syncthreads();
    }

    float bv[4];
#pragma unroll
    for (int ni = 0; ni < 4; ni++)
        bv[ni] = bias ? b2f(bias[colBase + wc * 64 + ni * 16 + lr]) : 0.f;

    const bool f32out = (fdt != nullptr) && (*fdt != 0u);
    if (f32out) {
#pragma unroll
        for (int mi = 0; mi < 4; mi++)
#pragma unroll
            for (int ni = 0; ni < 4; ni++)
#pragma unroll
                for (int rg = 0; rg < 4; rg++) {
                    int m = wr * 64 + mi * 16 + lq * 4 + rg;
                    int n = wc * 64 + ni * 16 + lr;
                    Cf[(rowBase + m) * (long)N + colBase + n] = acc[mi][ni][rg] + bv[ni];
                }
        return;
    }

#pragma unroll
    for (int mi = 0; mi < 4; mi++)
#pragma unroll
        for (int ni = 0; ni < 4; ni++)
#pragma unroll
            for (int rg = 0; rg < 4; rg++) {
                int m = wr * 64 + mi * 16 + lq * 4 + rg;
                int n = wc * 64 + ni * 16 + lr;
                sm[m * 128 + n] = f2b(acc[mi][ni][rg] + bv[ni]);
            }
    __syncthreads();
#pragma unroll
    for (int i = 0; i < 8; i++) {
        int idx = i * 2048 + tid * 8;
        int r = idx >> 7, c = idx & 127;
        *(u16x8*)(C + (rowBase + r) * N + colBase + c) = *(const u16x8*)&sm[idx];
    }
}

// ---------------------------------------------------------------------------
// GRU recurrence. Grid = 128 blocks x 512 threads (2x co-residency margin).
//   bi = blockIdx.x & 15 -> batch rows [bi*16, +16)
//   bj = blockIdx.x >> 4 -> hidden cols [bj*64, +64)
// Inside a block: column-half hf = tid>>8 (32 cols each), K-wave kw = (tid>>6)&3.
// Whh fragment-resident in registers; K split across the 4 kw-waves, partials
// reduced via padded LDS (duplicated per half). 8 blocks sharing bi couple
// step-to-step -> FLAG-ARRAY group barrier: each block sc-stores 1 into its
// own dword of a per-step 8-flag line (no atomic RMW serialization), thread0
// polls the line. All cross-block h traffic is LLC-coherent (sc0/sc1);
// __syncthreads' vmcnt(0) drain before the flag store is the release.
// ---------------------------------------------------------------------------
__global__ __launch_bounds__(512, 1) void gru_rec(
    const unsigned short* __restrict__ gi,   // [Tc][NB][G3] bf16 (bih folded in)
    const unsigned short* __restrict__ Whh,  // [G3][HD] bf16 (staged)
    const unsigned short* __restrict__ bhh,  // [G3] bf16 (staged)
    const float* __restrict__ keep,          // [LSEQ][NB]
    const unsigned short* __restrict__ mem,  // [NB][1024] bf16 (staged)
    unsigned short* __restrict__ hdb,        // [2][NB][HD] double buffer
    unsigned short* __restrict__ Y,          // [Tc][NB][HD] chunk-local bf16
    unsigned short* __restrict__ hnB,        // [NB][1024] bf16 out
    float* __restrict__ hnF,                 // [NB][1024] f32 out
    const unsigned* __restrict__ fdt,
    int t0, int Tc, int layerOff,
    unsigned* __restrict__ ctr) {            // (Tc+1)*16 slots, 32-dword stride
    const int tid = threadIdx.x;
    const int l = tid & 63, w8 = tid >> 6, lr = l & 15, lq = l >> 4;
    const int kw = w8 & 3;        // K-partition wave 0..3
    const int hf = w8 >> 2;       // column half 0..1
    const int bi = blockIdx.x & 15, bj = blockIdx.x >> 4;
    const int colbase = bj * 64 + hf * 32;
    const bool f32out = (*fdt != 0u);

    __shared__ float red[2][4][16][100];  // [half][kw][row][96 padded]

    // --- Whh fragments -> registers (one-time). fr = g*2+cf. ---
    bf16x8 wreg[6][4];
#pragma unroll
    for (int fr = 0; fr < 6; fr++) {
        int g = fr >> 1, cf = fr & 1;
        long row = (long)g * HD + colbase + cf * 16 + lr;
#pragma unroll
        for (int ks = 0; ks < 4; ks++) {
            int k = kw * 128 + ks * 32 + lq * 8;
            wreg[fr][ks] = *(const bf16x8*)(Whh + row * HD + k);
        }
    }

    const int tid8 = tid & 255;
    const int m = tid8 >> 4, c0 = (tid8 & 15) * 2;
    const int n_g = bi * 16 + m;
    const int ch = colbase + c0;   // this thread's column pair (within HD)
    float bh[3][2];
#pragma unroll
    for (int g = 0; g < 3; g++) {
        unsigned v = *(const unsigned*)(bhh + g * HD + ch);
        bh[g][0] = b2f((unsigned short)(v & 0xffffu));
        bh[g][1] = b2f((unsigned short)(v >> 16));
    }

    if (t0 == 0) {  // init h0 from memory (layer slice) into parity 0
        unsigned v = *(const unsigned*)(mem + (long)n_g * 1024 + layerOff + ch);
        cstore((unsigned*)(hdb + (long)n_g * HD + ch), v);
        __syncthreads();  // drain before arrival
        unsigned* slot = ctr + ((long)Tc * 16 + bi) * 32;
        if (tid == 0) {
            cstore(slot + bj, 1u);
            unsigned got;
            do {
                got = 0;
#pragma unroll
                for (int i = 0; i < 8; i++) got += cload(slot + i);
                if (got < 8) __builtin_amdgcn_s_sleep(1);
            } while (got < 8);
        }
        __syncthreads();
    }

    // own h pair carried in registers (bf16-rounded == what others read)
    float hpv[2];
    {
        unsigned hp0 = cload((const unsigned*)(hdb + (long)(t0 & 1) * NB * HD + (long)n_g * HD + ch));
        hpv[0] = b2f((unsigned short)(hp0 & 0xffffu));
        hpv[1] = b2f((unsigned short)(hp0 >> 16));
    }

    // prefetch gi/keep for first step
    unsigned gv[3];
    float kp;
    {
        const unsigned short* gp = gi + (long)n_g * G3;
#pragma unroll
        for (int g = 0; g < 3; g++) gv[g] = *(const unsigned*)(gp + g * HD + ch);
        kp = keep[(long)t0 * NB + n_g];
    }

    for (int t = t0; t < t0 + Tc; ++t) {
        const unsigned short* hc = hdb + (long)(t & 1) * NB * HD;
        unsigned short* hx = hdb + (long)((t + 1) & 1) * NB * HD;

        // coherent 16B loads of the h stripe (rows bi*16+lr, K-slice of kw)
        const unsigned* hrow = (const unsigned*)(hc + (long)(bi * 16 + lr) * HD);
        union { u32x4 u; bf16x8 v; } t0u, t1u, t2u, t3u;
        cload4x4(hrow + kw * 64 + 0 * 16 + lq * 4, hrow + kw * 64 + 1 * 16 + lq * 4,
                 hrow + kw * 64 + 2 * 16 + lq * 4, hrow + kw * 64 + 3 * 16 + lq * 4,
                 t0u.u, t1u.u, t2u.u, t3u.u);
        bf16x8 af[4] = { t0u.v, t1u.v, t2u.v, t3u.v };

        f32x4 acc[6] = {};
#pragma unroll
        for (int ks = 0; ks < 4; ks++)
#pragma unroll
            for (int fr = 0; fr < 6; fr++)
                acc[fr] = __builtin_amdgcn_mfma_f32_16x16x32_bf16(af[ks], wreg[fr][ks], acc[fr], 0, 0, 0);

#pragma unroll
        for (int fr = 0; fr < 6; fr++)
#pragma unroll
            for (int rg = 0; rg < 4; rg++)
                red[hf][kw][lq * 4 + rg][fr * 16 + lr] = acc[fr][rg];
        __syncthreads();

        float s[3][2];
#pragma unroll
        for (int g = 0; g < 3; g++) { s[g][0] = 0.f; s[g][1] = 0.f; }
#pragma unroll
        for (int ww = 0; ww < 4; ww++)
#pragma unroll
            for (int g = 0; g < 3; g++) {
                const float* p = &red[hf][ww][m][g * 32 + c0];
                s[g][0] += p[0];
                s[g][1] += p[1];
            }

        unsigned short yo[2], ho[2];
        float hcf[2];
#pragma unroll
        for (int j = 0; j < 2; j++) {
            float ir  = b2f((unsigned short)((gv[0] >> (16 * j)) & 0xffffu));
            float iz  = b2f((unsigned short)((gv[1] >> (16 * j)) & 0xffffu));
            float in_ = b2f((unsigned short)((gv[2] >> (16 * j)) & 0xffffu));
            float r = 1.f / (1.f + __expf(-(ir + s[0][j] + bh[0][j])));
            float z = 1.f / (1.f + __expf(-(iz + s[1][j] + bh[1][j])));
            float nn = fast_tanh(in_ + r * (s[2][j] + bh[2][j]));
            float hnew = (1.f - z) * nn + z * hpv[j];
            hcf[j] = hnew * kp;
            yo[j] = f2b(hnew);
            ho[j] = f2b(hcf[j]);
            hpv[j] = b2f(ho[j]);  // carry bf16-rounded h*keep for next step
        }
        unsigned ypack = (unsigned)yo[0] | ((unsigned)yo[1] << 16);
        unsigned hpack = (unsigned)ho[0] | ((unsigned)ho[1] << 16);
        *(unsigned*)(Y + ((long)(t - t0) * NB + n_g) * HD + ch) = ypack;   // cross-kernel
        cstore((unsigned*)(hx + (long)n_g * HD + ch), hpack);              // cross-block
        if (t == LSEQ - 1) {
            if (f32out) {
                hnF[(long)n_g * 1024 + layerOff + ch]     = hcf[0];
                hnF[(long)n_g * 1024 + layerOff + ch + 1] = hcf[1];
            } else {
                *(unsigned*)(hnB + (long)n_g * 1024 + layerOff + ch) = hpack;
            }
        }

        if (t + 1 < t0 + Tc) {
            __syncthreads();  // vmcnt(0): this block's h stores are in LLC
            unsigned* slot = ctr + ((long)(t - t0) * 16 + bi) * 32;
            if (tid == 0) cstore(slot + bj, 1u);  // arrive (fire-and-forget)
            // prefetch next step's gi/keep while the group converges
            const unsigned short* gp = gi + ((long)(t + 1 - t0) * NB + n_g) * G3;
#pragma unroll
            for (int g = 0; g < 3; g++) gv[g] = *(const unsigned*)(gp + g * HD + ch);
            kp = keep[(long)(t + 1) * NB + n_g];
            if (tid == 0) {
                unsigned got;
                do {
                    got = 0;
#pragma unroll
                    for (int i = 0; i < 8; i++) got += cload(slot + i);
                    if (got < 8) __builtin_amdgcn_s_sleep(1);
                } while (got < 8);
            }
            __syncthreads();
        }
    }
}

// ---------------------------------------------------------------------------
// Host launcher — dtype-adaptive chunked two-layer pipeline.
// ---------------------------------------------------------------------------
extern "C" void kernel_launch(void* const* d_in, const int* in_sizes, int n_in,
                              void* d_out, int out_size, void* d_ws, size_t ws_size,
                              hipStream_t stream) {
    const void* x    = d_in[0];
    const void* mem  = d_in[1];
    const void* done = d_in[2];
    const void* fsrc[11] = { mem, d_in[3], d_in[4], d_in[5], d_in[6],
                             d_in[7], d_in[8], d_in[9], d_in[10], d_in[11], d_in[12] };
    const long  fn[11]   = { (long)NB * 1024, (long)G3 * CIN, (long)G3 * HD, G3, G3,
                             (long)G3 * HD, (long)G3 * HD, G3, G3, (long)NOUT * HD, NOUT };

    unsigned short* outB = (unsigned short*)d_out;
    float*          outF = (float*)d_out;
    unsigned short* hnB  = outB + (size_t)LSEQ * NB * NOUT;
    float*          hnF  = outF + (size_t)LSEQ * NB * NOUT;

    char* ws = (char*)d_ws;
    const size_t oFlag = 0;                                   // fdt @ +0, done-flag @ +64
    const size_t oKeep = 256;                                 // 0.5 MB
    const size_t oCtr  = oKeep + (size_t)LSEQ * NB * 4;       // 4 MB
    const size_t oWC   = oCtr + (size_t)4 * 1024 * 1024;      // staged weights/mem
    size_t wcTot = 0;
    size_t wcOff[11];
    for (int i = 0; i < 11; i++) { wcOff[i] = wcTot; wcTot += (size_t)fn[i] * 2; wcTot = (wcTot + 255) & ~(size_t)255; }
    const size_t oHdb0 = oWC + wcTot;
    const size_t oHdb1 = oHdb0 + (size_t)2 * NB * HD * 2;
    const size_t oDyn  = oHdb1 + (size_t)2 * NB * HD * 2;

    int Tc = 4;
    const int cand[6] = {128, 64, 32, 16, 8, 4};
    for (int i = 0; i < 6; i++) {
        size_t need = oDyn + (size_t)cand[i] * NB * (CIN + G3 + 2 * HD) * 2;
        if (need <= ws_size) { Tc = cand[i]; break; }
    }
    const size_t oXC  = oDyn;
    const size_t oGI  = oXC + (size_t)Tc * NB * CIN * 2;
    const size_t oY0c = oGI + (size_t)Tc * NB * G3 * 2;
    const size_t oY1c = oY0c + (size_t)Tc * NB * HD * 2;

    unsigned*       FDT  = (unsigned*)(ws + oFlag);
    unsigned*       DFLG = (unsigned*)(ws + oFlag + 64);
    float*          KEEP = (float*)(ws + oKeep);
    unsigned*       CTR  = (unsigned*)(ws + oCtr);
    unsigned short* WC   = (unsigned short*)(ws + oWC);
    unsigned short* HDB0 = (unsigned short*)(ws + oHdb0);
    unsigned short* HDB1 = (unsigned short*)(ws + oHdb1);
    unsigned short* XC   = (unsigned short*)(ws + oXC);
    unsigned short* GIb  = (unsigned short*)(ws + oGI);
    unsigned short* Y0c  = (unsigned short*)(ws + oY0c);
    unsigned short* Y1c  = (unsigned short*)(ws + oY1c);

    unsigned short* MEMc = WC + wcOff[0] / 2;
    unsigned short* WIH0 = WC + wcOff[1] / 2;
    unsigned short* WHH0 = WC + wcOff[2] / 2;
    unsigned short* BIH0 = WC + wcOff[3] / 2;
    unsigned short* BHH0 = WC + wcOff[4] / 2;
    unsigned short* WIH1 = WC + wcOff[5] / 2;
    unsigned short* WHH1 = WC + wcOff[6] / 2;
    unsigned short* BIH1 = WC + wcOff[7] / 2;
    unsigned short* BHH1 = WC + wcOff[8] / 2;
    unsigned short* WPc  = WC + wcOff[9] / 2;
    unsigned short* BPc  = WC + wcOff[10] / 2;

    hipMemsetAsync(ws + oCtr, 0, (size_t)4 * 1024 * 1024, stream);
    detect_fdt<<<1, 256, 0, stream>>>((const unsigned short*)x, 4096, FDT);
    detect_done<<<1, 256, 0, stream>>>((const unsigned char*)done, in_sizes[2], DFLG);
    expand_done<<<(LSEQ * NB + 255) / 256, 256, 0, stream>>>(done, DFLG, KEEP, LSEQ * NB);

    for (int i = 0; i < 11; i++) {
        int blocks = (int)((fn[i] + 1023) / 1024);
        if (blocks > 2048) blocks = 2048;
        cast_bf16<<<blocks, 256, 0, stream>>>(fsrc[i], 0, WC + wcOff[i] / 2, fn[i], FDT);
    }

    size_t ctrWords = 0;
    const size_t ctrStep = (size_t)(Tc + 1) * 16 * 32;
    for (int t0 = 0; t0 < LSEQ; t0 += Tc) {
        const long xcN = (long)Tc * NB * CIN;
        cast_bf16<<<2048, 256, 0, stream>>>(x, (long)t0 * NB * CIN, XC, xcN, FDT);
        gemm_nt<<<dim3(G3 / 128, Tc * NB / 128), 256, 0, stream>>>(
            XC, WIH0, BIH0, GIb, nullptr, nullptr, Tc * NB, G3, CIN);
        gru_rec<<<128, 512, 0, stream>>>(GIb, WHH0, BHH0, KEEP, MEMc, HDB0,
                                         Y0c, hnB, hnF, FDT, t0, Tc, 0, CTR + ctrWords);
        ctrWords += ctrStep;
        gemm_nt<<<dim3(G3 / 128, Tc * NB / 128), 256, 0, stream>>>(
            Y0c, WIH1, BIH1, GIb, nullptr, nullptr, Tc * NB, G3, HD);
        gru_rec<<<128, 512, 0, stream>>>(GIb, WHH1, BHH1, KEEP, MEMc, HDB1,
                                         Y1c, hnB, hnF, FDT, t0, Tc, HD, CTR + ctrWords);
        ctrWords += ctrStep;
        gemm_nt<<<dim3(NOUT / 128, Tc * NB / 128), 256, 0, stream>>>(
            Y1c, WPc, BPc, outB + (size_t)t0 * NB * NOUT,
            outF + (size_t)t0 * NB * NOUT, FDT, Tc * NB, NOUT, HD);
    }
}

// Round 7
// 3514.733 us; speedup vs baseline: 1.0815x; 1.0815x over previous
//
#include <hip/hip_runtime.h>

// ---------------------------------------------------------------------------
// Problem constants
// ---------------------------------------------------------------------------
static constexpr int LSEQ = 512;   // timesteps
static constexpr int NB   = 256;   // batch
static constexpr int CIN  = 256;   // input dim
static constexpr int HD   = 512;   // hidden dim
static constexpr int G3   = 1536;  // 3*HD
static constexpr int NOUT = 256;   // output dim

typedef __attribute__((ext_vector_type(8))) short bf16x8;
typedef __attribute__((ext_vector_type(4))) float f32x4;
typedef __attribute__((ext_vector_type(8))) unsigned short u16x8;
typedef __attribute__((ext_vector_type(4))) unsigned u32x4;

#define DEVI __device__ __forceinline__

DEVI float b2f(unsigned short h) { return __uint_as_float(((unsigned)h) << 16); }
DEVI unsigned short f2b(float x) {
    unsigned u = __float_as_uint(x);
    return (unsigned short)((u + 0x7FFFu + ((u >> 16) & 1u)) >> 16);
}
DEVI float sigm(float v) { return 1.f / (1.f + __expf(-v)); }
DEVI float fast_tanh(float x) {
    x = fminf(10.f, fmaxf(-10.f, x));
    float e = __expf(-2.f * x);
    return (1.f - e) / (1.f + e);
}

// Device-coherent dword access (LLC coherence point; safe across XCDs).
DEVI unsigned cload(const unsigned* p) {
    return __hip_atomic_load(p, __ATOMIC_RELAXED, __HIP_MEMORY_SCOPE_AGENT);
}
DEVI void cstore(unsigned* p, unsigned v) {
    __hip_atomic_store(p, v, __ATOMIC_RELAXED, __HIP_MEMORY_SCOPE_AGENT);
}
DEVI bf16x8 asbf(u32x4 u) { union { u32x4 a; bf16x8 b; } c; c.a = u; return c.b; }

// ---------------------------------------------------------------------------
// Float-dtype detection (f32 vs bf16 harness data).
// ---------------------------------------------------------------------------
__global__ void detect_fdt(const unsigned short* __restrict__ x, int nHalf,
                           unsigned* __restrict__ fdt) {
    __shared__ unsigned big;
    if (threadIdx.x == 0) big = 0;
    __syncthreads();
    for (int i = threadIdx.x; i < nHalf; i += 256) {
        unsigned e = (x[i] >> 7) & 0xFFu;
        if (e >= 0xC0u) atomicOr(&big, 1u);
    }
    __syncthreads();
    if (threadIdx.x == 0) *fdt = big ? 1u : 0u;
}

__global__ void cast_bf16(const void* __restrict__ src, long srcOff,
                          unsigned short* __restrict__ dst, long n,
                          const unsigned* __restrict__ fdt) {
    long i = (long)blockIdx.x * 256 + threadIdx.x;
    long stride = (long)gridDim.x * 256;
    if (*fdt) {
        const float* s = (const float*)src + srcOff;
        for (; i < n; i += stride) dst[i] = f2b(s[i]);
    } else {
        const unsigned short* s = (const unsigned short*)src + srcOff;
        for (; i < n; i += stride) dst[i] = s[i];
    }
}

__global__ void detect_done(const unsigned char* __restrict__ d, int elems,
                            unsigned* __restrict__ flag) {
    __shared__ unsigned bad[4];
    int tid = threadIdx.x;
    if (tid < 4) bad[tid] = 0;
    __syncthreads();
    int nInt = elems >> 2;
    const unsigned* di = (const unsigned*)d;
    for (int i = tid; i < nInt; i += 256) {
        unsigned v = di[i];
        if (v > 1u) atomicOr(&bad[0], 1u);
        if (v != 0u && v != 0x3F800000u) atomicOr(&bad[1], 1u);
    }
    int nHalf = elems >> 1;
    const unsigned short* dh = (const unsigned short*)d;
    for (int i = tid; i < nHalf; i += 256) {
        unsigned short h = dh[i];
        if (h != 0 && h != 0x3F80) atomicOr(&bad[2], 1u);
    }
    __syncthreads();
    if (tid == 0) {
        unsigned f;
        if (!bad[0]) f = 0u;
        else if (!bad[1]) f = 3u;
        else if (!bad[2]) f = 2u;
        else f = 1u;
        *flag = f;
    }
}

__global__ void expand_done(const void* __restrict__ d, const unsigned* __restrict__ flag,
                            float* __restrict__ keep, int elems) {
    int i = blockIdx.x * 256 + threadIdx.x;
    if (i >= elems) return;
    unsigned f = *flag;
    float v;
    if (f == 0u)      v = (float)((const int*)d)[i];
    else if (f == 1u) v = (float)((const unsigned char*)d)[i];
    else if (f == 2u) v = b2f(((const unsigned short*)d)[i]);
    else              v = ((const float*)d)[i];
    keep[i] = 1.f - v;
}

// ---------------------------------------------------------------------------
// NT GEMM (projection only): C[M,N] = A[M,K]@B[N,K]^T + bias.
// ---------------------------------------------------------------------------
__global__ __launch_bounds__(256) void gemm_nt(
    const unsigned short* __restrict__ A, const unsigned short* __restrict__ B,
    const unsigned short* __restrict__ bias, unsigned short* __restrict__ C,
    float* __restrict__ Cf, const unsigned* __restrict__ fdt,
    int M, int N, int K) {
    __shared__ unsigned short sm[16384];
    const int tid = threadIdx.x;
    const int l = tid & 63, w = tid >> 6;
    const int lr = l & 15, lq = l >> 4;
    const int wr = w >> 1, wc = w & 1;
    const long rowBase = (long)blockIdx.y * 128;
    const long colBase = (long)blockIdx.x * 128;

    int qrow[4], qc8[4];
#pragma unroll
    for (int i = 0; i < 4; i++) {
        int q = (i * 4 + w) * 64 + l;
        qrow[i] = q >> 3;
        qc8[i] = (q & 7) * 8;
    }

    f32x4 acc[4][4] = {};

    for (int k0 = 0; k0 < K; k0 += 64) {
#pragma unroll
        for (int i = 0; i < 4; i++) {
            const unsigned short* sA = A + (rowBase + qrow[i]) * K + k0 + qc8[i];
            const unsigned short* sB = B + (colBase + qrow[i]) * K + k0 + qc8[i];
            __builtin_amdgcn_global_load_lds(
                (const __attribute__((address_space(1))) void*)sA,
                (__attribute__((address_space(3))) void*)(sm + (i * 4 + w) * 512), 16, 0, 0);
            __builtin_amdgcn_global_load_lds(
                (const __attribute__((address_space(1))) void*)sB,
                (__attribute__((address_space(3))) void*)(sm + 8192 + (i * 4 + w) * 512), 16, 0, 0);
        }
        __syncthreads();
#pragma unroll
        for (int ks = 0; ks < 2; ks++) {
            bf16x8 af[4], bfr[4];
#pragma unroll
            for (int mi = 0; mi < 4; mi++)
                af[mi] = *(const bf16x8*)&sm[(wr * 64 + mi * 16 + lr) * 64 + ks * 32 + lq * 8];
#pragma unroll
            for (int ni = 0; ni < 4; ni++)
                bfr[ni] = *(const bf16x8*)&sm[8192 + (wc * 64 + ni * 16 + lr) * 64 + ks * 32 + lq * 8];
#pragma unroll
            for (int mi = 0; mi < 4; mi++)
#pragma unroll
                for (int ni = 0; ni < 4; ni++)
                    acc[mi][ni] = __builtin_amdgcn_mfma_f32_16x16x32_bf16(
                        af[mi], bfr[ni], acc[mi][ni], 0, 0, 0);
        }
        __syncthreads();
    }

    float bv[4];
#pragma unroll
    for (int ni = 0; ni < 4; ni++)
        bv[ni] = bias ? b2f(bias[colBase + wc * 64 + ni * 16 + lr]) : 0.f;

    const bool f32out = (fdt != nullptr) && (*fdt != 0u);
    if (f32out) {
#pragma unroll
        for (int mi = 0; mi < 4; mi++)
#pragma unroll
            for (int ni = 0; ni < 4; ni++)
#pragma unroll
                for (int rg = 0; rg < 4; rg++) {
                    int mm = wr * 64 + mi * 16 + lq * 4 + rg;
                    int nn = wc * 64 + ni * 16 + lr;
                    Cf[(rowBase + mm) * (long)N + colBase + nn] = acc[mi][ni][rg] + bv[ni];
                }
        return;
    }

#pragma unroll
    for (int mi = 0; mi < 4; mi++)
#pragma unroll
        for (int ni = 0; ni < 4; ni++)
#pragma unroll
            for (int rg = 0; rg < 4; rg++) {
                int mm = wr * 64 + mi * 16 + lq * 4 + rg;
                int nn = wc * 64 + ni * 16 + lr;
                sm[mm * 128 + nn] = f2b(acc[mi][ni][rg] + bv[ni]);
            }
    __syncthreads();
#pragma unroll
    for (int i = 0; i < 8; i++) {
        int idx = i * 2048 + tid * 8;
        int r = idx >> 7, c = idx & 127;
        *(u16x8*)(C + (rowBase + r) * N + colBase + c) = *(const u16x8*)&sm[idx];
    }
}

// ---------------------------------------------------------------------------
// Fused two-layer GRU with 1-step layer pipelining.
// Grid 256 blocks x 256 threads: bi = blockIdx&15 (batch rows bi*16..+16),
// bj = blockIdx>>4 (hidden cols bj*32..+32). Global step s: L0 processes
// t = l0b+s (if < l0e), L1 processes u = l1b+s (if in [0,l1e)). L1 needs
// y0[u] (written by L0 one step earlier) + h1[u] -> 513 barrier steps total
// instead of 1024. gi0 = x@Wih0 and gi1 = y0@Wih1 are fused (weights in
// registers), so no bulk GI GEMMs and no gi HBM traffic.
// Barrier: flag line (16 dwords) per (step,bi); post = coherent store after
// __syncthreads drain; thread0 polls. All cross-block h/y0 traffic via
// sc0/sc1 (LLC). n-gate needs i/h separation -> 8 accs per layer:
// [0..3]=rz(g,cf) shared i+h, [4..5]=n_h(cf), [6..7]=n_x(cf).
// ---------------------------------------------------------------------------
__global__ __launch_bounds__(256, 1) void gru_fused(
    const void* __restrict__ xin,            // [L][NB][CIN] f32 or bf16
    const unsigned short* __restrict__ wih0, // [G3][CIN] staged bf16
    const unsigned short* __restrict__ whh0, // [G3][HD]
    const unsigned short* __restrict__ wih1, // [G3][HD]
    const unsigned short* __restrict__ whh1, // [G3][HD]
    const unsigned short* __restrict__ bih0, const unsigned short* __restrict__ bhh0,
    const unsigned short* __restrict__ bih1, const unsigned short* __restrict__ bhh1,
    const float* __restrict__ keep,          // [L][NB]
    const unsigned short* __restrict__ mem,  // [NB][1024]
    unsigned short* __restrict__ h0db,       // [2][NB][HD]
    unsigned short* __restrict__ h1db,       // [2][NB][HD]
    unsigned short* __restrict__ y0r,        // [2][NB][HD] ring
    unsigned short* __restrict__ Y1,         // [(rows)][NB][HD]
    unsigned short* __restrict__ hnB, float* __restrict__ hnF,
    const unsigned* __restrict__ fdt,
    int l0b, int l0e, int l1b, int l1e, int y1base, int firstChunk, int S,
    unsigned* __restrict__ ctr) {
    const int tid = threadIdx.x;
    const int l = tid & 63, kw = tid >> 6, lr = l & 15, lq = l >> 4;
    const int bi = blockIdx.x & 15, bj = blockIdx.x >> 4;
    const int colbase = bj * 32;
    const bool f32in = (*fdt != 0u);

    __shared__ float red[4][16][132];  // one phase at a time (33.8 KB)

    // --- weight fragments -> registers (one-time) ---
    bf16x8 w0h[6][4], w1h[6][4], w1i[6][4], w0i[6][2];
#pragma unroll
    for (int fr = 0; fr < 6; fr++) {
        int g = fr >> 1, cf = fr & 1;
        long row = (long)g * HD + colbase + cf * 16 + lr;
#pragma unroll
        for (int ks = 0; ks < 4; ks++) {
            int k = kw * 128 + ks * 32 + lq * 8;
            w0h[fr][ks] = *(const bf16x8*)(whh0 + row * HD + k);
            w1h[fr][ks] = *(const bf16x8*)(whh1 + row * HD + k);
            w1i[fr][ks] = *(const bf16x8*)(wih1 + row * HD + k);
        }
#pragma unroll
        for (int ks = 0; ks < 2; ks++) {
            int k2 = kw * 64 + ks * 32 + lq * 8;
            w0i[fr][ks] = *(const bf16x8*)(wih0 + row * CIN + k2);
        }
    }

    const int m = tid >> 4, c0 = (tid & 15) * 2;
    const int n_g = bi * 16 + m;
    const int ch = colbase + c0;

    float brz0[2][2], brz1[2][2], bnx0[2], bnh0[2], bnx1[2], bnh1[2];
#pragma unroll
    for (int g = 0; g < 2; g++)
#pragma unroll
        for (int j = 0; j < 2; j++) {
            brz0[g][j] = b2f(bih0[g * HD + ch + j]) + b2f(bhh0[g * HD + ch + j]);
            brz1[g][j] = b2f(bih1[g * HD + ch + j]) + b2f(bhh1[g * HD + ch + j]);
        }
#pragma unroll
    for (int j = 0; j < 2; j++) {
        bnx0[j] = b2f(bih0[2 * HD + ch + j]);
        bnh0[j] = b2f(bhh0[2 * HD + ch + j]);
        bnx1[j] = b2f(bih1[2 * HD + ch + j]);
        bnh1[j] = b2f(bhh1[2 * HD + ch + j]);
    }

    if (firstChunk) {  // h0,h1 init from memory into parity 0
        unsigned v0 = *(const unsigned*)(mem + (long)n_g * 1024 + ch);
        unsigned v1 = *(const unsigned*)(mem + (long)n_g * 1024 + 512 + ch);
        cstore((unsigned*)(h0db + (long)n_g * HD + ch), v0);
        cstore((unsigned*)(h1db + (long)n_g * HD + ch), v1);
        __syncthreads();  // drain before init post (line 0)
        if (tid == 0) cstore(ctr + (0 * 16 + bi) * 16 + bj, 1u);
    }

    // own h pairs in registers (bf16-rounded == what others read)
    float hp0[2], hp1[2];
    {
        unsigned v = cload((const unsigned*)(h0db + (long)(l0b & 1) * NB * HD + (long)n_g * HD + ch));
        hp0[0] = b2f((unsigned short)(v & 0xffffu));
        hp0[1] = b2f((unsigned short)(v >> 16));
        int u0 = (l1b < 0) ? 0 : l1b;
        unsigned w = cload((const unsigned*)(h1db + (long)(u0 & 1) * NB * HD + (long)n_g * HD + ch));
        hp1[0] = b2f((unsigned short)(w & 0xffffu));
        hp1[1] = b2f((unsigned short)(w >> 16));
    }

    for (int s = 0; s < S; ++s) {
        const int t = l0b + s, u = l1b + s;
        const bool doL0 = (t < l0e);
        const bool doL1 = (u >= 0) && (u < l1e);

        f32x4 acc[8] = {};
        float kp0 = 0.f, kp1 = 0.f;

        // ---- pre-poll: x load + gi0 MFMAs (no cross-block dependency) ----
        if (doL0) {
            kp0 = keep[(long)t * NB + n_g];
            bf16x8 xf0, xf1;
            if (f32in) {
                const float* xp = (const float*)xin + ((long)t * NB + bi * 16 + lr) * CIN + kw * 64 + lq * 8;
                f32x4 xa = *(const f32x4*)(xp);
                f32x4 xb = *(const f32x4*)(xp + 4);
                f32x4 xc = *(const f32x4*)(xp + 32);
                f32x4 xd = *(const f32x4*)(xp + 36);
#pragma unroll
                for (int e = 0; e < 4; e++) {
                    ((unsigned short*)&xf0)[e]     = f2b(xa[e]);
                    ((unsigned short*)&xf0)[4 + e] = f2b(xb[e]);
                    ((unsigned short*)&xf1)[e]     = f2b(xc[e]);
                    ((unsigned short*)&xf1)[4 + e] = f2b(xd[e]);
                }
            } else {
                const unsigned short* xp = (const unsigned short*)xin + ((long)t * NB + bi * 16 + lr) * CIN + kw * 64 + lq * 8;
                xf0 = *(const bf16x8*)xp;
                xf1 = *(const bf16x8*)(xp + 32);
            }
#pragma unroll
            for (int fr = 0; fr < 6; fr++) {
                int g = fr >> 1, cf = fr & 1;
                int dst = (g < 2) ? fr : (6 + cf);
                acc[dst] = __builtin_amdgcn_mfma_f32_16x16x32_bf16(xf0, w0i[fr][0], acc[dst], 0, 0, 0);
                acc[dst] = __builtin_amdgcn_mfma_f32_16x16x32_bf16(xf1, w0i[fr][1], acc[dst], 0, 0, 0);
            }
        }
        if (doL1) kp1 = keep[(long)u * NB + n_g];

        // ---- group barrier: poll line[s] (skip at s==0 for non-first chunk) ----
        if (!(s == 0 && !firstChunk)) {
            if (tid == 0) {
                const unsigned* line = ctr + ((long)s * 16 + bi) * 16;
                for (;;) {
                    unsigned sum = 0;
#pragma unroll
                    for (int i = 0; i < 16; i++) sum += cload(line + i);
                    if (sum >= 16u) break;
                    __builtin_amdgcn_s_sleep(1);
                }
            }
        }
        __syncthreads();

        // ---- 12 coherent dwordx4 loads in ONE vmcnt window ----
        const unsigned* h0p = (const unsigned*)h0db + (long)(t & 1) * NB * (HD / 2) +
                              (long)(bi * 16 + lr) * (HD / 2) + kw * 64 + lq * 4;
        const unsigned* h1p = (const unsigned*)h1db + (long)(u & 1) * NB * (HD / 2) +
                              (long)(bi * 16 + lr) * (HD / 2) + kw * 64 + lq * 4;
        const unsigned* y0p = (const unsigned*)y0r + (long)(u & 1) * NB * (HD / 2) +
                              (long)(bi * 16 + lr) * (HD / 2) + kw * 64 + lq * 4;
        u32x4 A0, A1, A2, A3, B0, B1, B2, B3, C0, C1, C2, C3;
        asm volatile(
            "global_load_dwordx4 %0, %4, off sc0 sc1\n\t"
            "global_load_dwordx4 %1, %4, off offset:64 sc0 sc1\n\t"
            "global_load_dwordx4 %2, %4, off offset:128 sc0 sc1\n\t"
            "global_load_dwordx4 %3, %4, off offset:192 sc0 sc1"
            : "=&v"(A0), "=&v"(A1), "=&v"(A2), "=&v"(A3) : "v"(h0p) : "memory");
        asm volatile(
            "global_load_dwordx4 %0, %4, off sc0 sc1\n\t"
            "global_load_dwordx4 %1, %4, off offset:64 sc0 sc1\n\t"
            "global_load_dwordx4 %2, %4, off offset:128 sc0 sc1\n\t"
            "global_load_dwordx4 %3, %4, off offset:192 sc0 sc1"
            : "=&v"(B0), "=&v"(B1), "=&v"(B2), "=&v"(B3) : "v"(h1p) : "memory");
        asm volatile(
            "global_load_dwordx4 %0, %4, off sc0 sc1\n\t"
            "global_load_dwordx4 %1, %4, off offset:64 sc0 sc1\n\t"
            "global_load_dwordx4 %2, %4, off offset:128 sc0 sc1\n\t"
            "global_load_dwordx4 %3, %4, off offset:192 sc0 sc1"
            : "=&v"(C0), "=&v"(C1), "=&v"(C2), "=&v"(C3) : "v"(y0p) : "memory");
        asm volatile("s_waitcnt vmcnt(0)"
            : "+v"(A0), "+v"(A1), "+v"(A2), "+v"(A3),
              "+v"(B0), "+v"(B1), "+v"(B2), "+v"(B3),
              "+v"(C0), "+v"(C1), "+v"(C2), "+v"(C3) :: "memory");
        __builtin_amdgcn_sched_barrier(0);

        // ---- phase A: L0 h-MFMAs + red write ----
        if (doL0) {
            bf16x8 af[4] = { asbf(A0), asbf(A1), asbf(A2), asbf(A3) };
#pragma unroll
            for (int ks = 0; ks < 4; ks++)
#pragma unroll
                for (int fr = 0; fr < 6; fr++) {
                    int g = fr >> 1, cf = fr & 1;
                    int dst = (g < 2) ? fr : (4 + cf);
                    acc[dst] = __builtin_amdgcn_mfma_f32_16x16x32_bf16(af[ks], w0h[fr][ks], acc[dst], 0, 0, 0);
                }
#pragma unroll
            for (int f = 0; f < 8; f++)
#pragma unroll
                for (int rg = 0; rg < 4; rg++)
                    red[kw][lq * 4 + rg][f * 16 + lr] = acc[f][rg];
        }
        __syncthreads();

        float s0r[2], s0z[2], s0nh[2], s0nx[2];
        if (doL0) {
            s0r[0] = s0r[1] = s0z[0] = s0z[1] = 0.f;
            s0nh[0] = s0nh[1] = s0nx[0] = s0nx[1] = 0.f;
#pragma unroll
            for (int ww = 0; ww < 4; ww++) {
                const float* p = &red[ww][m][0];
                s0r[0] += p[c0];      s0r[1] += p[c0 + 1];
                s0z[0] += p[32 + c0]; s0z[1] += p[33 + c0];
                s0nh[0] += p[64 + c0]; s0nh[1] += p[65 + c0];
                s0nx[0] += p[96 + c0]; s0nx[1] += p[97 + c0];
            }
        }
        __syncthreads();  // WAR: phase B overwrites red

        // ---- phase B: L1 (gi1 = y0@Wih1 fused) + red write ----
        if (doL1) {
#pragma unroll
            for (int f = 0; f < 8; f++) acc[f] = f32x4{0.f, 0.f, 0.f, 0.f};
            bf16x8 afh[4] = { asbf(B0), asbf(B1), asbf(B2), asbf(B3) };
            bf16x8 afy[4] = { asbf(C0), asbf(C1), asbf(C2), asbf(C3) };
#pragma unroll
            for (int ks = 0; ks < 4; ks++)
#pragma unroll
                for (int fr = 0; fr < 6; fr++) {
                    int g = fr >> 1, cf = fr & 1;
                    int dh = (g < 2) ? fr : (4 + cf);
                    int dy = (g < 2) ? fr : (6 + cf);
                    acc[dh] = __builtin_amdgcn_mfma_f32_16x16x32_bf16(afh[ks], w1h[fr][ks], acc[dh], 0, 0, 0);
                    acc[dy] = __builtin_amdgcn_mfma_f32_16x16x32_bf16(afy[ks], w1i[fr][ks], acc[dy], 0, 0, 0);
                }
#pragma unroll
            for (int f = 0; f < 8; f++)
#pragma unroll
                for (int rg = 0; rg < 4; rg++)
                    red[kw][lq * 4 + rg][f * 16 + lr] = acc[f][rg];
        }
        __syncthreads();

        float s1r[2], s1z[2], s1nh[2], s1nx[2];
        if (doL1) {
            s1r[0] = s1r[1] = s1z[0] = s1z[1] = 0.f;
            s1nh[0] = s1nh[1] = s1nx[0] = s1nx[1] = 0.f;
#pragma unroll
            for (int ww = 0; ww < 4; ww++) {
                const float* p = &red[ww][m][0];
                s1r[0] += p[c0];      s1r[1] += p[c0 + 1];
                s1z[0] += p[32 + c0]; s1z[1] += p[33 + c0];
                s1nh[0] += p[64 + c0]; s1nh[1] += p[65 + c0];
                s1nx[0] += p[96 + c0]; s1nx[1] += p[97 + c0];
            }
        }

        // ---- gates + stores ----
        if (doL0) {
            unsigned short ys[2], hs[2];
            float hc[2];
#pragma unroll
            for (int j = 0; j < 2; j++) {
                float r = sigm(s0r[j] + brz0[0][j]);
                float z = sigm(s0z[j] + brz0[1][j]);
                float n = fast_tanh((s0nx[j] + bnx0[j]) + r * (s0nh[j] + bnh0[j]));
                float h = (1.f - z) * n + z * hp0[j];
                ys[j] = f2b(h);
                hc[j] = h * kp0;
                hs[j] = f2b(hc[j]);
                hp0[j] = b2f(hs[j]);
            }
            unsigned yp = (unsigned)ys[0] | ((unsigned)ys[1] << 16);
            unsigned hp = (unsigned)hs[0] | ((unsigned)hs[1] << 16);
            cstore((unsigned*)(y0r + (long)(t & 1) * NB * HD + (long)n_g * HD + ch), yp);
            cstore((unsigned*)(h0db + (long)((t + 1) & 1) * NB * HD + (long)n_g * HD + ch), hp);
            if (t == LSEQ - 1) {
                if (f32in) {
                    hnF[(long)n_g * 1024 + ch] = hc[0];
                    hnF[(long)n_g * 1024 + ch + 1] = hc[1];
                } else {
                    *(unsigned*)(hnB + (long)n_g * 1024 + ch) = hp;
                }
            }
        }
        if (doL1) {
            unsigned short ys[2], hs[2];
            float hc[2];
#pragma unroll
            for (int j = 0; j < 2; j++) {
                float r = sigm(s1r[j] + brz1[0][j]);
                float z = sigm(s1z[j] + brz1[1][j]);
                float n = fast_tanh((s1nx[j] + bnx1[j]) + r * (s1nh[j] + bnh1[j]));
                float h = (1.f - z) * n + z * hp1[j];
                ys[j] = f2b(h);
                hc[j] = h * kp1;
                hs[j] = f2b(hc[j]);
                hp1[j] = b2f(hs[j]);
            }
            unsigned yp = (unsigned)ys[0] | ((unsigned)ys[1] << 16);
            unsigned hp = (unsigned)hs[0] | ((unsigned)hs[1] << 16);
            *(unsigned*)(Y1 + ((long)(u - y1base) * NB + n_g) * HD + ch) = yp;  // cross-kernel
            cstore((unsigned*)(h1db + (long)((u + 1) & 1) * NB * HD + (long)n_g * HD + ch), hp);
            if (u == LSEQ - 1) {
                if (f32in) {
                    hnF[(long)n_g * 1024 + 512 + ch] = hc[0];
                    hnF[(long)n_g * 1024 + 512 + ch + 1] = hc[1];
                } else {
                    *(unsigned*)(hnB + (long)n_g * 1024 + 512 + ch) = hp;
                }
            }
        }

        __syncthreads();  // vmcnt(0) drain: all block stores in LLC
        if (tid == 0) cstore(ctr + ((long)(s + 1) * 16 + bi) * 16 + bj, 1u);
    }
}

// ---------------------------------------------------------------------------
// Host launcher.
// ---------------------------------------------------------------------------
static inline int imax(int a, int b) { return a > b ? a : b; }
static inline int imin(int a, int b) { return a < b ? a : b; }

extern "C" void kernel_launch(void* const* d_in, const int* in_sizes, int n_in,
                              void* d_out, int out_size, void* d_ws, size_t ws_size,
                              hipStream_t stream) {
    const void* x    = d_in[0];
    const void* mem  = d_in[1];
    const void* done = d_in[2];
    const void* fsrc[11] = { mem, d_in[3], d_in[4], d_in[5], d_in[6],
                             d_in[7], d_in[8], d_in[9], d_in[10], d_in[11], d_in[12] };
    const long  fn[11]   = { (long)NB * 1024, (long)G3 * CIN, (long)G3 * HD, G3, G3,
                             (long)G3 * HD, (long)G3 * HD, G3, G3, (long)NOUT * HD, NOUT };

    unsigned short* outB = (unsigned short*)d_out;
    float*          outF = (float*)d_out;
    unsigned short* hnB  = outB + (size_t)LSEQ * NB * NOUT;
    float*          hnF  = outF + (size_t)LSEQ * NB * NOUT;

    char* ws = (char*)d_ws;
    const size_t oFlag = 0;                                  // fdt @ +0, done-flag @ +64
    const size_t oKeep = 256;                                // 0.5 MB
    const size_t oCtr  = oKeep + (size_t)LSEQ * NB * 4;      // 2 MB barrier flag lines
    const size_t oWC   = oCtr + (size_t)2 * 1024 * 1024;
    size_t wcTot = 0;
    size_t wcOff[11];
    for (int i = 0; i < 11; i++) {
        wcOff[i] = wcTot;
        wcTot += (size_t)fn[i] * 2;
        wcTot = (wcTot + 255) & ~(size_t)255;
    }
    const size_t oH0  = oWC + wcTot;
    const size_t oH1  = oH0 + (size_t)2 * NB * HD * 2;
    const size_t oY0R = oH1 + (size_t)2 * NB * HD * 2;
    const size_t oY1  = oY0R + (size_t)2 * NB * HD * 2;

    int Tc = 32;
    const int cand[5] = {512, 256, 128, 64, 32};
    for (int i = 0; i < 5; i++) {
        size_t need = oY1 + (size_t)(cand[i] + 2) * NB * HD * 2;
        if (need <= ws_size) { Tc = cand[i]; break; }
    }

    unsigned*       FDT  = (unsigned*)(ws + oFlag);
    unsigned*       DFLG = (unsigned*)(ws + oFlag + 64);
    float*          KEEP = (float*)(ws + oKeep);
    unsigned*       CTR  = (unsigned*)(ws + oCtr);
    unsigned short* WC   = (unsigned short*)(ws + oWC);
    unsigned short* H0DB = (unsigned short*)(ws + oH0);
    unsigned short* H1DB = (unsigned short*)(ws + oH1);
    unsigned short* Y0R  = (unsigned short*)(ws + oY0R);
    unsigned short* Y1c  = (unsigned short*)(ws + oY1);

    unsigned short* MEMc = WC + wcOff[0] / 2;
    unsigned short* WIH0 = WC + wcOff[1] / 2;
    unsigned short* WHH0 = WC + wcOff[2] / 2;
    unsigned short* BIH0 = WC + wcOff[3] / 2;
    unsigned short* BHH0 = WC + wcOff[4] / 2;
    unsigned short* WIH1 = WC + wcOff[5] / 2;
    unsigned short* WHH1 = WC + wcOff[6] / 2;
    unsigned short* BIH1 = WC + wcOff[7] / 2;
    unsigned short* BHH1 = WC + wcOff[8] / 2;
    unsigned short* WPc  = WC + wcOff[9] / 2;
    unsigned short* BPc  = WC + wcOff[10] / 2;

    hipMemsetAsync(ws + oCtr, 0, (size_t)2 * 1024 * 1024, stream);
    detect_fdt<<<1, 256, 0, stream>>>((const unsigned short*)x, 4096, FDT);
    detect_done<<<1, 256, 0, stream>>>((const unsigned char*)done, in_sizes[2], DFLG);
    expand_done<<<(LSEQ * NB + 255) / 256, 256, 0, stream>>>(done, DFLG, KEEP, LSEQ * NB);

    for (int i = 0; i < 11; i++) {
        int blocks = (int)((fn[i] + 1023) / 1024);
        if (blocks > 2048) blocks = 2048;
        cast_bf16<<<blocks, 256, 0, stream>>>(fsrc[i], 0, WC + wcOff[i] / 2, fn[i], FDT);
    }

    size_t ctrOff = 0;
    for (int t0 = 0, c = 0; t0 < LSEQ; t0 += Tc, c++) {
        int l0b = t0, l0e = imin(LSEQ, t0 + Tc);
        int l1b = t0 - 1;
        int l1e = (l0e == LSEQ) ? LSEQ : (l0e - 1);
        int S = imax(l0e - l0b, l1e - l1b);
        int y1base = l1b < 0 ? 0 : l1b;

        gru_fused<<<256, 256, 0, stream>>>(
            x, WIH0, WHH0, WIH1, WHH1, BIH0, BHH0, BIH1, BHH1,
            KEEP, MEMc, H0DB, H1DB, Y0R, Y1c, hnB, hnF, FDT,
            l0b, l0e, l1b, l1e, y1base, (c == 0) ? 1 : 0, S, CTR + ctrOff);
        ctrOff += (size_t)(S + 2) * 16 * 16;

        int urows = (l1e - y1base) * NB;
        gemm_nt<<<dim3(NOUT / 128, urows / 128), 256, 0, stream>>>(
            Y1c, WPc, BPc, outB + (size_t)y1base * NB * NOUT,
            outF + (size_t)y1base * NB * NOUT, FDT, urows, NOUT, HD);
    }
}

// Round 11
// 3376.845 us; speedup vs baseline: 1.1256x; 1.0408x over previous
//
#include <hip/hip_runtime.h>

// ---------------------------------------------------------------------------
// Problem constants
// ---------------------------------------------------------------------------
static constexpr int LSEQ = 512;   // timesteps
static constexpr int NB   = 256;   // batch
static constexpr int CIN  = 256;   // input dim
static constexpr int HD   = 512;   // hidden dim
static constexpr int G3   = 1536;  // 3*HD
static constexpr int NOUT = 256;   // output dim

typedef __attribute__((ext_vector_type(8))) short bf16x8;
typedef __attribute__((ext_vector_type(4))) float f32x4;
typedef __attribute__((ext_vector_type(8))) unsigned short u16x8;
typedef __attribute__((ext_vector_type(4))) unsigned u32x4;

#define DEVI __device__ __forceinline__

DEVI float b2f(unsigned short h) { return __uint_as_float(((unsigned)h) << 16); }
DEVI unsigned short f2b(float x) {
    unsigned u = __float_as_uint(x);
    return (unsigned short)((u + 0x7FFFu + ((u >> 16) & 1u)) >> 16);
}

// Device-coherent dword access (LLC coherence point; safe across XCDs).
// Compiler-visible atomics -> __syncthreads drains them (validated r4-r7).
DEVI unsigned cload(const unsigned* p) {
    return __hip_atomic_load(p, __ATOMIC_RELAXED, __HIP_MEMORY_SCOPE_AGENT);
}
DEVI void cstore(unsigned* p, unsigned v) {
    __hip_atomic_store(p, v, __ATOMIC_RELAXED, __HIP_MEMORY_SCOPE_AGENT);
}

// exp-based tanh: no libm branches.
DEVI float fast_tanh(float x) {
    x = fminf(10.f, fmaxf(-10.f, x));
    float e = __expf(-2.f * x);
    return (1.f - e) / (1.f + e);
}

// 4x coherent 16B loads (LLC), one waitcnt. sched_barrier guards against the
// compiler hoisting register-only consumers past the inline-asm waitcnt.
DEVI void cload4x4(const unsigned* p0, const unsigned* p1,
                   const unsigned* p2, const unsigned* p3,
                   u32x4& r0, u32x4& r1, u32x4& r2, u32x4& r3) {
    asm volatile(
        "global_load_dwordx4 %0, %4, off sc0 sc1\n\t"
        "global_load_dwordx4 %1, %5, off sc0 sc1\n\t"
        "global_load_dwordx4 %2, %6, off sc0 sc1\n\t"
        "global_load_dwordx4 %3, %7, off sc0 sc1\n\t"
        "s_waitcnt vmcnt(0)"
        : "=&v"(r0), "=&v"(r1), "=&v"(r2), "=&v"(r3)
        : "v"(p0), "v"(p1), "v"(p2), "v"(p3)
        : "memory");
    __builtin_amdgcn_sched_barrier(0);
}

// ---------------------------------------------------------------------------
// Float-dtype detection: if data is f32, the low u16 of each float is random
// mantissa bits -> "bf16" exponent field >= 0xC0 (|v|>=2^65) ~25% of the time.
// ---------------------------------------------------------------------------
__global__ void detect_fdt(const unsigned short* __restrict__ x, int nHalf,
                           unsigned* __restrict__ fdt) {
    __shared__ unsigned big;
    if (threadIdx.x == 0) big = 0;
    __syncthreads();
    for (int i = threadIdx.x; i < nHalf; i += 256) {
        unsigned e = (x[i] >> 7) & 0xFFu;
        if (e >= 0xC0u) atomicOr(&big, 1u);
    }
    __syncthreads();
    if (threadIdx.x == 0) *fdt = big ? 1u : 0u;
}

// Cast a float tensor (f32 or bf16 per *fdt) to a bf16 staging buffer.
__global__ void cast_bf16(const void* __restrict__ src, long srcOff,
                          unsigned short* __restrict__ dst, long n,
                          const unsigned* __restrict__ fdt) {
    long i = (long)blockIdx.x * 256 + threadIdx.x;
    long stride = (long)gridDim.x * 256;
    if (*fdt) {
        const float* s = (const float*)src + srcOff;
        for (; i < n; i += stride) dst[i] = f2b(s[i]);
    } else {
        const unsigned short* s = (const unsigned short*)src + srcOff;
        for (; i < n; i += stride) dst[i] = s[i];
    }
}

// ---------------------------------------------------------------------------
// done-mask dtype detection (bool/int8 vs int32 vs bf16 vs f32)
// ---------------------------------------------------------------------------
__global__ void detect_done(const unsigned char* __restrict__ d, int elems,
                            unsigned* __restrict__ flag) {
    __shared__ unsigned bad[4];
    int tid = threadIdx.x;
    if (tid < 4) bad[tid] = 0;
    __syncthreads();
    int nInt = elems >> 2;
    const unsigned* di = (const unsigned*)d;
    for (int i = tid; i < nInt; i += 256) {
        unsigned v = di[i];
        if (v > 1u) atomicOr(&bad[0], 1u);
        if (v != 0u && v != 0x3F800000u) atomicOr(&bad[1], 1u);
    }
    int nHalf = elems >> 1;
    const unsigned short* dh = (const unsigned short*)d;
    for (int i = tid; i < nHalf; i += 256) {
        unsigned short h = dh[i];
        if (h != 0 && h != 0x3F80) atomicOr(&bad[2], 1u);
    }
    __syncthreads();
    if (tid == 0) {
        unsigned f;
        if (!bad[0]) f = 0u;       // int32 0/1
        else if (!bad[1]) f = 3u;  // float32
        else if (!bad[2]) f = 2u;  // bf16
        else f = 1u;               // bytes (bool / int8)
        *flag = f;
    }
}

__global__ void expand_done(const void* __restrict__ d, const unsigned* __restrict__ flag,
                            float* __restrict__ keep, int elems) {
    int i = blockIdx.x * 256 + threadIdx.x;
    if (i >= elems) return;
    unsigned f = *flag;
    float v;
    if (f == 0u)      v = (float)((const int*)d)[i];
    else if (f == 1u) v = (float)((const unsigned char*)d)[i];
    else if (f == 2u) v = b2f(((const unsigned short*)d)[i]);
    else              v = ((const float*)d)[i];
    keep[i] = 1.f - v;
}

// ---------------------------------------------------------------------------
// NT GEMM: C[M,N] = A[M,K] @ B[N,K]^T + bias, bf16 in, f32 accum.
// m97-style: 128x128 tile, BK=64, 4 waves, 16x16x32 MFMA, global_load_lds.
// Output: bf16 to C (LDS-staged coalesced) OR f32 to Cf when *fdt!=0.
// ---------------------------------------------------------------------------
__global__ __launch_bounds__(256) void gemm_nt(
    const unsigned short* __restrict__ A, const unsigned short* __restrict__ B,
    const unsigned short* __restrict__ bias, unsigned short* __restrict__ C,
    float* __restrict__ Cf, const unsigned* __restrict__ fdt,
    int M, int N, int K) {
    __shared__ unsigned short sm[16384];  // A: [0,8192), B: [8192,16384)
    const int tid = threadIdx.x;
    const int l = tid & 63, w = tid >> 6;
    const int lr = l & 15, lq = l >> 4;
    const int wr = w >> 1, wc = w & 1;
    const long rowBase = (long)blockIdx.y * 128;
    const long colBase = (long)blockIdx.x * 128;

    int qrow[4], qc8[4];
#pragma unroll
    for (int i = 0; i < 4; i++) {
        int q = (i * 4 + w) * 64 + l;  // 16B-chunk id within the 128x64 tile
        qrow[i] = q >> 3;
        qc8[i] = (q & 7) * 8;
    }

    f32x4 acc[4][4] = {};

    for (int k0 = 0; k0 < K; k0 += 64) {
#pragma unroll
        for (int i = 0; i < 4; i++) {
            const unsigned short* sA = A + (rowBase + qrow[i]) * K + k0 + qc8[i];
            const unsigned short* sB = B + (colBase + qrow[i]) * K + k0 + qc8[i];
            __builtin_amdgcn_global_load_lds(
                (const __attribute__((address_space(1))) void*)sA,
                (__attribute__((address_space(3))) void*)(sm + (i * 4 + w) * 512), 16, 0, 0);
            __builtin_amdgcn_global_load_lds(
                (const __attribute__((address_space(1))) void*)sB,
                (__attribute__((address_space(3))) void*)(sm + 8192 + (i * 4 + w) * 512), 16, 0, 0);
        }
        __syncthreads();
#pragma unroll
        for (int ks = 0; ks < 2; ks++) {
            bf16x8 af[4], bfr[4];
#pragma unroll
            for (int mi = 0; mi < 4; mi++)
                af[mi] = *(const bf16x8*)&sm[(wr * 64 + mi * 16 + lr) * 64 + ks * 32 + lq * 8];
#pragma unroll
            for (int ni = 0; ni < 4; ni++)
                bfr[ni] = *(const bf16x8*)&sm[8192 + (wc * 64 + ni * 16 + lr) * 64 + ks * 32 + lq * 8];
#pragma unroll
            for (int mi = 0; mi < 4; mi++)
#pragma unroll
                for (int ni = 0; ni < 4; ni++)
                    acc[mi][ni] = __builtin_amdgcn_mfma_f32_16x16x32_bf16(
                        af[mi], bfr[ni], acc[mi][ni], 0, 0, 0);
        }
        __syncthreads();
    }

    float bv[4];
#pragma unroll
    for (int ni = 0; ni < 4; ni++)
        bv[ni] = bias ? b2f(bias[colBase + wc * 64 + ni * 16 + lr]) : 0.f;

    const bool f32out = (fdt != nullptr) && (*fdt != 0u);
    if (f32out) {
#pragma unroll
        for (int mi = 0; mi < 4; mi++)
#pragma unroll
            for (int ni = 0; ni < 4; ni++)
#pragma unroll
                for (int rg = 0; rg < 4; rg++) {
                    int m = wr * 64 + mi * 16 + lq * 4 + rg;
                    int n = wc * 64 + ni * 16 + lr;
                    Cf[(rowBase + m) * (long)N + colBase + n] = acc[mi][ni][rg] + bv[ni];
                }
        return;
    }

#pragma unroll
    for (int mi = 0; mi < 4; mi++)
#pragma unroll
        for (int ni = 0; ni < 4; ni++)
#pragma unroll
            for (int rg = 0; rg < 4; rg++) {
                int m = wr * 64 + mi * 16 + lq * 4 + rg;
                int n = wc * 64 + ni * 16 + lr;
                sm[m * 128 + n] = f2b(acc[mi][ni][rg] + bv[ni]);
            }
    __syncthreads();
#pragma unroll
    for (int i = 0; i < 8; i++) {
        int idx = i * 2048 + tid * 8;
        int r = idx >> 7, c = idx & 127;
        *(u16x8*)(C + (rowBase + r) * N + colBase + c) = *(const u16x8*)&sm[idx];
    }
}

// ---------------------------------------------------------------------------
// GRU recurrence — ROUND-5 base (passed, 2.48us/step) with ONE delta:
// the group barrier's 16-way serialized fetch_add chain is replaced by a
// 16-flag line: thread0 posts its own flag dword (compiler-visible cstore,
// drained by the preceding __syncthreads), then ALL waves' lanes 0-15 poll
// the line. Both surrounding __syncthreads kept.
// Grid = 256 blocks x 256 threads; bi = blockIdx&15 (batch rows bi*16..+16),
// bj = blockIdx>>4 (hidden cols bj*32..+32). Whh fragment-resident in regs;
// K split across 4 waves, partials reduced via padded LDS. All cross-block
// h traffic LLC-coherent.
// ---------------------------------------------------------------------------
DEVI void groupbar(unsigned* slot, int bj, int l) {
    __syncthreads();  // drains this block's coherent (atomic) stores
    if (threadIdx.x == 0) cstore(slot + bj, 1u);  // arrive: own flag dword
    unsigned v;
    do { v = (l < 16) ? cload(slot + l) : 1u; } while (!__all(v != 0u));
    __syncthreads();
}

__global__ __launch_bounds__(256, 1) void gru_rec(
    const unsigned short* __restrict__ gi,   // [Tc][NB][G3] bf16 (bih folded in)
    const unsigned short* __restrict__ Whh,  // [G3][HD] bf16 (staged)
    const unsigned short* __restrict__ bhh,  // [G3] bf16 (staged)
    const float* __restrict__ keep,          // [LSEQ][NB]
    const unsigned short* __restrict__ mem,  // [NB][1024] bf16 (staged)
    unsigned short* __restrict__ hdb,        // [2][NB][HD] double buffer
    unsigned short* __restrict__ Y,          // [Tc][NB][HD] chunk-local bf16
    unsigned short* __restrict__ hnB,        // [NB][1024] bf16 out
    float* __restrict__ hnF,                 // [NB][1024] f32 out
    const unsigned* __restrict__ fdt,
    int t0, int Tc, int layerOff,
    unsigned* __restrict__ ctr) {            // (Tc+1)*16 slots, 32-dword stride
    const int tid = threadIdx.x;
    const int l = tid & 63, w = tid >> 6, lr = l & 15, lq = l >> 4;
    const int bi = blockIdx.x & 15, bj = blockIdx.x >> 4;
    const bool f32out = (*fdt != 0u);

    __shared__ float red[4][16][100];  // padded stride

    // --- Whh fragments -> registers (one-time) ---
    bf16x8 wreg[6][4];
#pragma unroll
    for (int fr = 0; fr < 6; fr++) {
        int g = fr >> 1, cf = fr & 1;
        long row = (long)g * HD + bj * 32 + cf * 16 + lr;
#pragma unroll
        for (int ks = 0; ks < 4; ks++) {
            int k = w * 128 + ks * 32 + lq * 8;
            wreg[fr][ks] = *(const bf16x8*)(Whh + row * HD + k);
        }
    }

    const int m = tid >> 4, c0 = (tid & 15) * 2;
    const int n_g = bi * 16 + m;
    const int ch = bj * 32 + c0;
    float bh[3][2];
#pragma unroll
    for (int g = 0; g < 3; g++) {
        unsigned v = *(const unsigned*)(bhh + g * HD + ch);
        bh[g][0] = b2f((unsigned short)(v & 0xffffu));
        bh[g][1] = b2f((unsigned short)(v >> 16));
    }

    if (t0 == 0) {  // init h0 from memory (layer slice) into parity 0
        unsigned v = *(const unsigned*)(mem + (long)n_g * 1024 + layerOff + ch);
        cstore((unsigned*)(hdb + (long)n_g * HD + ch), v);
        groupbar(ctr + ((long)Tc * 16 + bi) * 32, bj, l);
    }

    // own h pair carried in registers (bf16-rounded == what others read)
    float hpv[2];
    {
        unsigned hp0 = cload((const unsigned*)(hdb + (long)(t0 & 1) * NB * HD + (long)n_g * HD + ch));
        hpv[0] = b2f((unsigned short)(hp0 & 0xffffu));
        hpv[1] = b2f((unsigned short)(hp0 >> 16));
    }

    // prefetch gi/keep for first step
    unsigned gv[3];
    float kp;
    {
        const unsigned short* gp = gi + (long)n_g * G3;
#pragma unroll
        for (int g = 0; g < 3; g++) gv[g] = *(const unsigned*)(gp + g * HD + ch);
        kp = keep[(long)t0 * NB + n_g];
    }

    for (int t = t0; t < t0 + Tc; ++t) {
        const unsigned short* hc = hdb + (long)(t & 1) * NB * HD;
        unsigned short* hx = hdb + (long)((t + 1) & 1) * NB * HD;

        // coherent 16B loads of the h stripe (written by other blocks)
        const unsigned* hrow = (const unsigned*)(hc + (long)(bi * 16 + lr) * HD);
        union { u32x4 u; bf16x8 v; } t0u, t1u, t2u, t3u;
        cload4x4(hrow + w * 64 + 0 * 16 + lq * 4, hrow + w * 64 + 1 * 16 + lq * 4,
                 hrow + w * 64 + 2 * 16 + lq * 4, hrow + w * 64 + 3 * 16 + lq * 4,
                 t0u.u, t1u.u, t2u.u, t3u.u);
        bf16x8 af[4] = { t0u.v, t1u.v, t2u.v, t3u.v };

        f32x4 acc[6] = {};
#pragma unroll
        for (int ks = 0; ks < 4; ks++)
#pragma unroll
            for (int fr = 0; fr < 6; fr++)
                acc[fr] = __builtin_amdgcn_mfma_f32_16x16x32_bf16(af[ks], wreg[fr][ks], acc[fr], 0, 0, 0);

#pragma unroll
        for (int fr = 0; fr < 6; fr++)
#pragma unroll
            for (int rg = 0; rg < 4; rg++)
                red[w][lq * 4 + rg][fr * 16 + lr] = acc[fr][rg];
        __syncthreads();

        float s[3][2];
#pragma unroll
        for (int g = 0; g < 3; g++) { s[g][0] = 0.f; s[g][1] = 0.f; }
#pragma unroll
        for (int ww = 0; ww < 4; ww++)
#pragma unroll
            for (int g = 0; g < 3; g++) {
                const float* p = &red[ww][m][g * 32 + c0];
                s[g][0] += p[0];
                s[g][1] += p[1];
            }

        unsigned short yo[2], ho[2];
        float hcf[2];
#pragma unroll
        for (int j = 0; j < 2; j++) {
            float ir  = b2f((unsigned short)((gv[0] >> (16 * j)) & 0xffffu));
            float iz  = b2f((unsigned short)((gv[1] >> (16 * j)) & 0xffffu));
            float in_ = b2f((unsigned short)((gv[2] >> (16 * j)) & 0xffffu));
            float r = 1.f / (1.f + __expf(-(ir + s[0][j] + bh[0][j])));
            float z = 1.f / (1.f + __expf(-(iz + s[1][j] + bh[1][j])));
            float nn = fast_tanh(in_ + r * (s[2][j] + bh[2][j]));
            float hnew = (1.f - z) * nn + z * hpv[j];
            hcf[j] = hnew * kp;
            yo[j] = f2b(hnew);
            ho[j] = f2b(hcf[j]);
            hpv[j] = b2f(ho[j]);  // carry bf16-rounded h*keep for next step
        }
        unsigned ypack = (unsigned)yo[0] | ((unsigned)yo[1] << 16);
        unsigned hpack = (unsigned)ho[0] | ((unsigned)ho[1] << 16);
        *(unsigned*)(Y + ((long)(t - t0) * NB + n_g) * HD + ch) = ypack;   // cross-kernel
        cstore((unsigned*)(hx + (long)n_g * HD + ch), hpack);              // cross-block
        if (t == LSEQ - 1) {
            if (f32out) {
                hnF[(long)n_g * 1024 + layerOff + ch]     = hcf[0];
                hnF[(long)n_g * 1024 + layerOff + ch + 1] = hcf[1];
            } else {
                *(unsigned*)(hnB + (long)n_g * 1024 + layerOff + ch) = hpack;
            }
        }

        if (t + 1 < t0 + Tc) {
            // prefetch next step's gi/keep (independent of h), then group barrier
            const unsigned short* gp = gi + ((long)(t + 1 - t0) * NB + n_g) * G3;
#pragma unroll
            for (int g = 0; g < 3; g++) gv[g] = *(const unsigned*)(gp + g * HD + ch);
            kp = keep[(long)(t + 1) * NB + n_g];
            groupbar(ctr + ((long)(t - t0) * 16 + bi) * 32, bj, l);
        }
    }
}

// ---------------------------------------------------------------------------
// Host launcher — dtype-adaptive chunked two-layer pipeline (round-5 exact).
// ---------------------------------------------------------------------------
extern "C" void kernel_launch(void* const* d_in, const int* in_sizes, int n_in,
                              void* d_out, int out_size, void* d_ws, size_t ws_size,
                              hipStream_t stream) {
    const void* x    = d_in[0];
    const void* mem  = d_in[1];
    const void* done = d_in[2];
    const void* fsrc[11] = { mem, d_in[3], d_in[4], d_in[5], d_in[6],
                             d_in[7], d_in[8], d_in[9], d_in[10], d_in[11], d_in[12] };
    const long  fn[11]   = { (long)NB * 1024, (long)G3 * CIN, (long)G3 * HD, G3, G3,
                             (long)G3 * HD, (long)G3 * HD, G3, G3, (long)NOUT * HD, NOUT };

    unsigned short* outB = (unsigned short*)d_out;
    float*          outF = (float*)d_out;
    unsigned short* hnB  = outB + (size_t)LSEQ * NB * NOUT;
    float*          hnF  = outF + (size_t)LSEQ * NB * NOUT;

    char* ws = (char*)d_ws;
    const size_t oFlag = 0;                                   // fdt @ +0, done-flag @ +64
    const size_t oKeep = 256;
    const size_t oCtr  = oKeep + (size_t)LSEQ * NB * 4;       // 4 MB barrier slots
    const size_t oWC   = oCtr + (size_t)4 * 1024 * 1024;      // staged weights/mem
    size_t wcTot = 0;
    size_t wcOff[11];
    for (int i = 0; i < 11; i++) { wcOff[i] = wcTot; wcTot += (size_t)fn[i] * 2; wcTot = (wcTot + 255) & ~(size_t)255; }
    const size_t oHdb0 = oWC + wcTot;
    const size_t oHdb1 = oHdb0 + (size_t)2 * NB * HD * 2;
    const size_t oDyn  = oHdb1 + (size_t)2 * NB * HD * 2;

    int Tc = 4;
    const int cand[6] = {128, 64, 32, 16, 8, 4};
    for (int i = 0; i < 6; i++) {
        size_t need = oDyn + (size_t)cand[i] * NB * (CIN + G3 + 2 * HD) * 2;
        if (need <= ws_size) { Tc = cand[i]; break; }
    }
    const size_t oXC  = oDyn;
    const size_t oGI  = oXC + (size_t)Tc * NB * CIN * 2;
    const size_t oY0c = oGI + (size_t)Tc * NB * G3 * 2;
    const size_t oY1c = oY0c + (size_t)Tc * NB * HD * 2;

    unsigned*       FDT  = (unsigned*)(ws + oFlag);
    unsigned*       DFLG = (unsigned*)(ws + oFlag + 64);
    float*          KEEP = (float*)(ws + oKeep);
    unsigned*       CTR  = (unsigned*)(ws + oCtr);
    unsigned short* WC   = (unsigned short*)(ws + oWC);
    unsigned short* HDB0 = (unsigned short*)(ws + oHdb0);
    unsigned short* HDB1 = (unsigned short*)(ws + oHdb1);
    unsigned short* XC   = (unsigned short*)(ws + oXC);
    unsigned short* GIb  = (unsigned short*)(ws + oGI);
    unsigned short* Y0c  = (unsigned short*)(ws + oY0c);
    unsigned short* Y1c  = (unsigned short*)(ws + oY1c);

    unsigned short* MEMc = WC + wcOff[0] / 2;
    unsigned short* WIH0 = WC + wcOff[1] / 2;
    unsigned short* WHH0 = WC + wcOff[2] / 2;
    unsigned short* BIH0 = WC + wcOff[3] / 2;
    unsigned short* BHH0 = WC + wcOff[4] / 2;
    unsigned short* WIH1 = WC + wcOff[5] / 2;
    unsigned short* WHH1 = WC + wcOff[6] / 2;
    unsigned short* BIH1 = WC + wcOff[7] / 2;
    unsigned short* BHH1 = WC + wcOff[8] / 2;
    unsigned short* WPc  = WC + wcOff[9] / 2;
    unsigned short* BPc  = WC + wcOff[10] / 2;

    hipMemsetAsync(ws + oCtr, 0, (size_t)4 * 1024 * 1024, stream);
    detect_fdt<<<1, 256, 0, stream>>>((const unsigned short*)x, 4096, FDT);
    detect_done<<<1, 256, 0, stream>>>((const unsigned char*)done, in_sizes[2], DFLG);
    expand_done<<<(LSEQ * NB + 255) / 256, 256, 0, stream>>>(done, DFLG, KEEP, LSEQ * NB);

    for (int i = 0; i < 11; i++) {
        int blocks = (int)((fn[i] + 1023) / 1024);
        if (blocks > 2048) blocks = 2048;
        cast_bf16<<<blocks, 256, 0, stream>>>(fsrc[i], 0, WC + wcOff[i] / 2, fn[i], FDT);
    }

    size_t ctrWords = 0;
    const size_t ctrStep = (size_t)(Tc + 1) * 16 * 32;
    for (int t0 = 0; t0 < LSEQ; t0 += Tc) {
        const long xcN = (long)Tc * NB * CIN;
        cast_bf16<<<2048, 256, 0, stream>>>(x, (long)t0 * NB * CIN, XC, xcN, FDT);
        gemm_nt<<<dim3(G3 / 128, Tc * NB / 128), 256, 0, stream>>>(
            XC, WIH0, BIH0, GIb, nullptr, nullptr, Tc * NB, G3, CIN);
        gru_rec<<<256, 256, 0, stream>>>(GIb, WHH0, BHH0, KEEP, MEMc, HDB0,
                                         Y0c, hnB, hnF, FDT, t0, Tc, 0, CTR + ctrWords);
        ctrWords += ctrStep;
        gemm_nt<<<dim3(G3 / 128, Tc * NB / 128), 256, 0, stream>>>(
            Y0c, WIH1, BIH1, GIb, nullptr, nullptr, Tc * NB, G3, HD);
        gru_rec<<<256, 256, 0, stream>>>(GIb, WHH1, BHH1, KEEP, MEMc, HDB1,
                                         Y1c, hnB, hnF, FDT, t0, Tc, HD, CTR + ctrWords);
        ctrWords += ctrStep;
        gemm_nt<<<dim3(NOUT / 128, Tc * NB / 128), 256, 0, stream>>>(
            Y1c, WPc, BPc, outB + (size_t)t0 * NB * NOUT,
            outF + (size_t)t0 * NB * NOUT, FDT, Tc * NB, NOUT, HD);
    }
}

// Round 13
// 3100.986 us; speedup vs baseline: 1.2258x; 1.0890x over previous
//
#include <hip/hip_runtime.h>

// ---------------------------------------------------------------------------
// Problem constants
// ---------------------------------------------------------------------------
static constexpr int LSEQ = 512;   // timesteps
static constexpr int NB   = 256;   // batch
static constexpr int CIN  = 256;   // input dim
static constexpr int HD   = 512;   // hidden dim
static constexpr int G3   = 1536;  // 3*HD
static constexpr int NOUT = 256;   // output dim

typedef __attribute__((ext_vector_type(8))) short bf16x8;
typedef __attribute__((ext_vector_type(4))) float f32x4;
typedef __attribute__((ext_vector_type(8))) unsigned short u16x8;
typedef __attribute__((ext_vector_type(4))) unsigned u32x4;

#define DEVI __device__ __forceinline__

DEVI float b2f(unsigned short h) { return __uint_as_float(((unsigned)h) << 16); }
DEVI unsigned short f2b(float x) {
    unsigned u = __float_as_uint(x);
    return (unsigned short)((u + 0x7FFFu + ((u >> 16) & 1u)) >> 16);
}

// LLC-coherent (cross-XCD safe) dword access — THE validated flavor
// (r4-r7, r11). sc0-only "XCD-local" retired permanently: r8 stale reads,
// r12 barrier deadlock (sc0 stores not visible to other CUs' sc0 loads).
DEVI unsigned cload(const unsigned* p) {
    return __hip_atomic_load(p, __ATOMIC_RELAXED, __HIP_MEMORY_SCOPE_AGENT);
}
DEVI void cstore(unsigned* p, unsigned v) {
    __hip_atomic_store(p, v, __ATOMIC_RELAXED, __HIP_MEMORY_SCOPE_AGENT);
}

// exp-based tanh: no libm branches.
DEVI float fast_tanh(float x) {
    x = fminf(10.f, fmaxf(-10.f, x));
    float e = __expf(-2.f * x);
    return (1.f - e) / (1.f + e);
}

// 4x coherent 16B loads (LLC), one waitcnt. sched_barrier guards against the
// compiler hoisting register-only consumers past the inline-asm waitcnt.
DEVI void cload4x4(const unsigned* p0, const unsigned* p1,
                   const unsigned* p2, const unsigned* p3,
                   u32x4& r0, u32x4& r1, u32x4& r2, u32x4& r3) {
    asm volatile(
        "global_load_dwordx4 %0, %4, off sc0 sc1\n\t"
        "global_load_dwordx4 %1, %5, off sc0 sc1\n\t"
        "global_load_dwordx4 %2, %6, off sc0 sc1\n\t"
        "global_load_dwordx4 %3, %7, off sc0 sc1\n\t"
        "s_waitcnt vmcnt(0)"
        : "=&v"(r0), "=&v"(r1), "=&v"(r2), "=&v"(r3)
        : "v"(p0), "v"(p1), "v"(p2), "v"(p3)
        : "memory");
    __builtin_amdgcn_sched_barrier(0);
}

// ---------------------------------------------------------------------------
// Float-dtype detection (f32 vs bf16 harness data).
// ---------------------------------------------------------------------------
__global__ void detect_fdt(const unsigned short* __restrict__ x, int nHalf,
                           unsigned* __restrict__ fdt) {
    __shared__ unsigned big;
    if (threadIdx.x == 0) big = 0;
    __syncthreads();
    for (int i = threadIdx.x; i < nHalf; i += 256) {
        unsigned e = (x[i] >> 7) & 0xFFu;
        if (e >= 0xC0u) atomicOr(&big, 1u);
    }
    __syncthreads();
    if (threadIdx.x == 0) *fdt = big ? 1u : 0u;
}

__global__ void cast_bf16(const void* __restrict__ src, long srcOff,
                          unsigned short* __restrict__ dst, long n,
                          const unsigned* __restrict__ fdt) {
    long i = (long)blockIdx.x * 256 + threadIdx.x;
    long stride = (long)gridDim.x * 256;
    if (*fdt) {
        const float* s = (const float*)src + srcOff;
        for (; i < n; i += stride) dst[i] = f2b(s[i]);
    } else {
        const unsigned short* s = (const unsigned short*)src + srcOff;
        for (; i < n; i += stride) dst[i] = s[i];
    }
}

__global__ void detect_done(const unsigned char* __restrict__ d, int elems,
                            unsigned* __restrict__ flag) {
    __shared__ unsigned bad[4];
    int tid = threadIdx.x;
    if (tid < 4) bad[tid] = 0;
    __syncthreads();
    int nInt = elems >> 2;
    const unsigned* di = (const unsigned*)d;
    for (int i = tid; i < nInt; i += 256) {
        unsigned v = di[i];
        if (v > 1u) atomicOr(&bad[0], 1u);
        if (v != 0u && v != 0x3F800000u) atomicOr(&bad[1], 1u);
    }
    int nHalf = elems >> 1;
    const unsigned short* dh = (const unsigned short*)d;
    for (int i = tid; i < nHalf; i += 256) {
        unsigned short h = dh[i];
        if (h != 0 && h != 0x3F80) atomicOr(&bad[2], 1u);
    }
    __syncthreads();
    if (tid == 0) {
        unsigned f;
        if (!bad[0]) f = 0u;       // int32 0/1
        else if (!bad[1]) f = 3u;  // float32
        else if (!bad[2]) f = 2u;  // bf16
        else f = 1u;               // bytes (bool / int8)
        *flag = f;
    }
}

__global__ void expand_done(const void* __restrict__ d, const unsigned* __restrict__ flag,
                            float* __restrict__ keep, int elems) {
    int i = blockIdx.x * 256 + threadIdx.x;
    if (i >= elems) return;
    unsigned f = *flag;
    float v;
    if (f == 0u)      v = (float)((const int*)d)[i];
    else if (f == 1u) v = (float)((const unsigned char*)d)[i];
    else if (f == 2u) v = b2f(((const unsigned short*)d)[i]);
    else              v = ((const float*)d)[i];
    keep[i] = 1.f - v;
}

// ---------------------------------------------------------------------------
// NT GEMM: C[M,N] = A[M,K] @ B[N,K]^T + bias, bf16 in, f32 accum.
// m97-style: 128x128 tile, BK=64, 4 waves, 16x16x32 MFMA, global_load_lds.
// Output: bf16 to C (LDS-staged coalesced) OR f32 to Cf when *fdt!=0.
// ---------------------------------------------------------------------------
__global__ __launch_bounds__(256) void gemm_nt(
    const unsigned short* __restrict__ A, const unsigned short* __restrict__ B,
    const unsigned short* __restrict__ bias, unsigned short* __restrict__ C,
    float* __restrict__ Cf, const unsigned* __restrict__ fdt,
    int M, int N, int K) {
    __shared__ unsigned short sm[16384];  // A: [0,8192), B: [8192,16384)
    const int tid = threadIdx.x;
    const int l = tid & 63, w = tid >> 6;
    const int lr = l & 15, lq = l >> 4;
    const int wr = w >> 1, wc = w & 1;
    const long rowBase = (long)blockIdx.y * 128;
    const long colBase = (long)blockIdx.x * 128;

    int qrow[4], qc8[4];
#pragma unroll
    for (int i = 0; i < 4; i++) {
        int q = (i * 4 + w) * 64 + l;  // 16B-chunk id within the 128x64 tile
        qrow[i] = q >> 3;
        qc8[i] = (q & 7) * 8;
    }

    f32x4 acc[4][4] = {};

    for (int k0 = 0; k0 < K; k0 += 64) {
#pragma unroll
        for (int i = 0; i < 4; i++) {
            const unsigned short* sA = A + (rowBase + qrow[i]) * K + k0 + qc8[i];
            const unsigned short* sB = B + (colBase + qrow[i]) * K + k0 + qc8[i];
            __builtin_amdgcn_global_load_lds(
                (const __attribute__((address_space(1))) void*)sA,
                (__attribute__((address_space(3))) void*)(sm + (i * 4 + w) * 512), 16, 0, 0);
            __builtin_amdgcn_global_load_lds(
                (const __attribute__((address_space(1))) void*)sB,
                (__attribute__((address_space(3))) void*)(sm + 8192 + (i * 4 + w) * 512), 16, 0, 0);
        }
        __syncthreads();
#pragma unroll
        for (int ks = 0; ks < 2; ks++) {
            bf16x8 af[4], bfr[4];
#pragma unroll
            for (int mi = 0; mi < 4; mi++)
                af[mi] = *(const bf16x8*)&sm[(wr * 64 + mi * 16 + lr) * 64 + ks * 32 + lq * 8];
#pragma unroll
            for (int ni = 0; ni < 4; ni++)
                bfr[ni] = *(const bf16x8*)&sm[8192 + (wc * 64 + ni * 16 + lr) * 64 + ks * 32 + lq * 8];
#pragma unroll
            for (int mi = 0; mi < 4; mi++)
#pragma unroll
                for (int ni = 0; ni < 4; ni++)
                    acc[mi][ni] = __builtin_amdgcn_mfma_f32_16x16x32_bf16(
                        af[mi], bfr[ni], acc[mi][ni], 0, 0, 0);
        }
        __syncthreads();
    }

    float bv[4];
#pragma unroll
    for (int ni = 0; ni < 4; ni++)
        bv[ni] = bias ? b2f(bias[colBase + wc * 64 + ni * 16 + lr]) : 0.f;

    const bool f32out = (fdt != nullptr) && (*fdt != 0u);
    if (f32out) {
#pragma unroll
        for (int mi = 0; mi < 4; mi++)
#pragma unroll
            for (int ni = 0; ni < 4; ni++)
#pragma unroll
                for (int rg = 0; rg < 4; rg++) {
                    int m = wr * 64 + mi * 16 + lq * 4 + rg;
                    int n = wc * 64 + ni * 16 + lr;
                    Cf[(rowBase + m) * (long)N + colBase + n] = acc[mi][ni][rg] + bv[ni];
                }
        return;
    }

#pragma unroll
    for (int mi = 0; mi < 4; mi++)
#pragma unroll
        for (int ni = 0; ni < 4; ni++)
#pragma unroll
            for (int rg = 0; rg < 4; rg++) {
                int m = wr * 64 + mi * 16 + lq * 4 + rg;
                int n = wc * 64 + ni * 16 + lr;
                sm[m * 128 + n] = f2b(acc[mi][ni][rg] + bv[ni]);
            }
    __syncthreads();
#pragma unroll
    for (int i = 0; i < 8; i++) {
        int idx = i * 2048 + tid * 8;
        int r = idx >> 7, c = idx & 127;
        *(u16x8*)(C + (rowBase + r) * N + colBase + c) = *(const u16x8*)&sm[idx];
    }
}

// ---------------------------------------------------------------------------
// GRU recurrence — round-5 base (PASSED, 317us/dispatch) with ONE delta:
// the group barrier is SPLIT into arrive/wait, and the non-barrier-gated
// work (Y store, hn store, next-step gi/keep prefetch) moves between the
// arrive (post) and the wait (spin). The barrier drain then covers only the
// h cstore; Y-ack and gi-load latency overlap the poll RTT. The
// post->prefetch->poll ordering ran correctly in round 6.
// Grid = 256 blocks x 256 threads; bi = blockIdx&15 (batch rows bi*16..+16),
// bj = blockIdx>>4 (hidden cols bj*32..+32). Whh fragment-resident in regs;
// K split across 4 waves, partials reduced via padded LDS. All cross-block
// h traffic LLC-coherent, compiler-visible atomics.
// ---------------------------------------------------------------------------
DEVI void groupbar_full(unsigned* wptr) {  // used only for the t0==0 init
    __syncthreads();
    if (threadIdx.x == 0) {
        __hip_atomic_fetch_add(wptr, 1u, __ATOMIC_RELAXED, __HIP_MEMORY_SCOPE_AGENT);
        while (__hip_atomic_load(wptr, __ATOMIC_RELAXED, __HIP_MEMORY_SCOPE_AGENT) < 16u)
            __builtin_amdgcn_s_sleep(1);
    }
    __syncthreads();
}

__global__ __launch_bounds__(256, 1) void gru_rec(
    const unsigned short* __restrict__ gi,   // [Tc][NB][G3] bf16 (bih folded in)
    const unsigned short* __restrict__ Whh,  // [G3][HD] bf16 (staged)
    const unsigned short* __restrict__ bhh,  // [G3] bf16 (staged)
    const float* __restrict__ keep,          // [LSEQ][NB]
    const unsigned short* __restrict__ mem,  // [NB][1024] bf16 (staged)
    unsigned short* __restrict__ hdb,        // [2][NB][HD] double buffer
    unsigned short* __restrict__ Y,          // [Tc][NB][HD] chunk-local bf16
    unsigned short* __restrict__ hnB,        // [NB][1024] bf16 out
    float* __restrict__ hnF,                 // [NB][1024] f32 out
    const unsigned* __restrict__ fdt,
    int t0, int Tc, int layerOff,
    unsigned* __restrict__ ctr) {            // (Tc+1)*16 slots, 32-dword stride
    const int tid = threadIdx.x;
    const int l = tid & 63, w = tid >> 6, lr = l & 15, lq = l >> 4;
    const int bi = blockIdx.x & 15, bj = blockIdx.x >> 4;
    const bool f32out = (*fdt != 0u);

    __shared__ float red[4][16][100];  // padded stride

    // --- Whh fragments -> registers (one-time) ---
    bf16x8 wreg[6][4];
#pragma unroll
    for (int fr = 0; fr < 6; fr++) {
        int g = fr >> 1, cf = fr & 1;
        long row = (long)g * HD + bj * 32 + cf * 16 + lr;
#pragma unroll
        for (int ks = 0; ks < 4; ks++) {
            int k = w * 128 + ks * 32 + lq * 8;
            wreg[fr][ks] = *(const bf16x8*)(Whh + row * HD + k);
        }
    }

    const int m = tid >> 4, c0 = (tid & 15) * 2;
    const int n_g = bi * 16 + m;
    const int ch = bj * 32 + c0;
    float bh[3][2];
#pragma unroll
    for (int g = 0; g < 3; g++) {
        unsigned v = *(const unsigned*)(bhh + g * HD + ch);
        bh[g][0] = b2f((unsigned short)(v & 0xffffu));
        bh[g][1] = b2f((unsigned short)(v >> 16));
    }

    if (t0 == 0) {  // init h0 from memory (layer slice) into parity 0
        unsigned v = *(const unsigned*)(mem + (long)n_g * 1024 + layerOff + ch);
        cstore((unsigned*)(hdb + (long)n_g * HD + ch), v);
        groupbar_full(ctr + ((long)Tc * 16 + bi) * 32);
    }

    // own h pair carried in registers (bf16-rounded == what others read)
    float hpv[2];
    {
        unsigned hp0 = cload((const unsigned*)(hdb + (long)(t0 & 1) * NB * HD + (long)n_g * HD + ch));
        hpv[0] = b2f((unsigned short)(hp0 & 0xffffu));
        hpv[1] = b2f((unsigned short)(hp0 >> 16));
    }

    // prefetch gi/keep for first step
    unsigned gv[3];
    float kp;
    {
        const unsigned short* gp = gi + (long)n_g * G3;
#pragma unroll
        for (int g = 0; g < 3; g++) gv[g] = *(const unsigned*)(gp + g * HD + ch);
        kp = keep[(long)t0 * NB + n_g];
    }

    for (int t = t0; t < t0 + Tc; ++t) {
        const unsigned short* hc = hdb + (long)(t & 1) * NB * HD;
        unsigned short* hx = hdb + (long)((t + 1) & 1) * NB * HD;

        // coherent 16B loads of the h stripe (written by other blocks)
        const unsigned* hrow = (const unsigned*)(hc + (long)(bi * 16 + lr) * HD);
        union { u32x4 u; bf16x8 v; } t0u, t1u, t2u, t3u;
        cload4x4(hrow + w * 64 + 0 * 16 + lq * 4, hrow + w * 64 + 1 * 16 + lq * 4,
                 hrow + w * 64 + 2 * 16 + lq * 4, hrow + w * 64 + 3 * 16 + lq * 4,
                 t0u.u, t1u.u, t2u.u, t3u.u);
        bf16x8 af[4] = { t0u.v, t1u.v, t2u.v, t3u.v };

        f32x4 acc[6] = {};
#pragma unroll
        for (int ks = 0; ks < 4; ks++)
#pragma unroll
            for (int fr = 0; fr < 6; fr++)
                acc[fr] = __builtin_amdgcn_mfma_f32_16x16x32_bf16(af[ks], wreg[fr][ks], acc[fr], 0, 0, 0);

#pragma unroll
        for (int fr = 0; fr < 6; fr++)
#pragma unroll
            for (int rg = 0; rg < 4; rg++)
                red[w][lq * 4 + rg][fr * 16 + lr] = acc[fr][rg];
        __syncthreads();

        float s[3][2];
#pragma unroll
        for (int g = 0; g < 3; g++) { s[g][0] = 0.f; s[g][1] = 0.f; }
#pragma unroll
        for (int ww = 0; ww < 4; ww++)
#pragma unroll
            for (int g = 0; g < 3; g++) {
                const float* p = &red[ww][m][g * 32 + c0];
                s[g][0] += p[0];
                s[g][1] += p[1];
            }

        unsigned short yo[2], ho[2];
        float hcf[2];
#pragma unroll
        for (int j = 0; j < 2; j++) {
            float ir  = b2f((unsigned short)((gv[0] >> (16 * j)) & 0xffffu));
            float iz  = b2f((unsigned short)((gv[1] >> (16 * j)) & 0xffffu));
            float in_ = b2f((unsigned short)((gv[2] >> (16 * j)) & 0xffffu));
            float r = 1.f / (1.f + __expf(-(ir + s[0][j] + bh[0][j])));
            float z = 1.f / (1.f + __expf(-(iz + s[1][j] + bh[1][j])));
            float nn = fast_tanh(in_ + r * (s[2][j] + bh[2][j]));
            float hnew = (1.f - z) * nn + z * hpv[j];
            hcf[j] = hnew * kp;
            yo[j] = f2b(hnew);
            ho[j] = f2b(hcf[j]);
            hpv[j] = b2f(ho[j]);  // carry bf16-rounded h*keep for next step
        }
        unsigned ypack = (unsigned)yo[0] | ((unsigned)yo[1] << 16);
        unsigned hpack = (unsigned)ho[0] | ((unsigned)ho[1] << 16);

        // barrier-gated store FIRST: the cross-block h state (atomic, visible)
        cstore((unsigned*)(hx + (long)n_g * HD + ch), hpack);

        const bool last = (t + 1 >= t0 + Tc);
        unsigned* slot = ctr + ((long)(t - t0) * 16 + bi) * 32;
        if (!last) {
            __syncthreads();  // drains the h cstore (vmcnt(0) before s_barrier)
            if (tid == 0)     // arrive
                __hip_atomic_fetch_add(slot, 1u, __ATOMIC_RELAXED, __HIP_MEMORY_SCOPE_AGENT);
        }

        // ---- non-barrier-gated work, overlapped with group arrival ----
        *(unsigned*)(Y + ((long)(t - t0) * NB + n_g) * HD + ch) = ypack;  // cross-kernel
        if (t == LSEQ - 1) {
            if (f32out) {
                hnF[(long)n_g * 1024 + layerOff + ch]     = hcf[0];
                hnF[(long)n_g * 1024 + layerOff + ch + 1] = hcf[1];
            } else {
                *(unsigned*)(hnB + (long)n_g * 1024 + layerOff + ch) = hpack;
            }
        }
        if (!last) {
            // prefetch next step's gi/keep (independent of h) under the poll
            const unsigned short* gp = gi + ((long)(t + 1 - t0) * NB + n_g) * G3;
#pragma unroll
            for (int g = 0; g < 3; g++) gv[g] = *(const unsigned*)(gp + g * HD + ch);
            kp = keep[(long)(t + 1) * NB + n_g];
            // wait
            if (tid == 0) {
                while (__hip_atomic_load(slot, __ATOMIC_RELAXED, __HIP_MEMORY_SCOPE_AGENT) < 16u)
                    __builtin_amdgcn_s_sleep(1);
            }
            __syncthreads();
        }
    }
}

// ---------------------------------------------------------------------------
// Host launcher — dtype-adaptive chunked two-layer pipeline (round-5 exact).
// ---------------------------------------------------------------------------
extern "C" void kernel_launch(void* const* d_in, const int* in_sizes, int n_in,
                              void* d_out, int out_size, void* d_ws, size_t ws_size,
                              hipStream_t stream) {
    const void* x    = d_in[0];
    const void* mem  = d_in[1];
    const void* done = d_in[2];
    const void* fsrc[11] = { mem, d_in[3], d_in[4], d_in[5], d_in[6],
                             d_in[7], d_in[8], d_in[9], d_in[10], d_in[11], d_in[12] };
    const long  fn[11]   = { (long)NB * 1024, (long)G3 * CIN, (long)G3 * HD, G3, G3,
                             (long)G3 * HD, (long)G3 * HD, G3, G3, (long)NOUT * HD, NOUT };

    unsigned short* outB = (unsigned short*)d_out;
    float*          outF = (float*)d_out;
    unsigned short* hnB  = outB + (size_t)LSEQ * NB * NOUT;
    float*          hnF  = outF + (size_t)LSEQ * NB * NOUT;

    char* ws = (char*)d_ws;
    const size_t oFlag = 0;                                   // fdt @ +0, done-flag @ +64
    const size_t oKeep = 256;
    const size_t oCtr  = oKeep + (size_t)LSEQ * NB * 4;       // 4 MB barrier slots
    const size_t oWC   = oCtr + (size_t)4 * 1024 * 1024;      // staged weights/mem
    size_t wcTot = 0;
    size_t wcOff[11];
    for (int i = 0; i < 11; i++) { wcOff[i] = wcTot; wcTot += (size_t)fn[i] * 2; wcTot = (wcTot + 255) & ~(size_t)255; }
    const size_t oHdb0 = oWC + wcTot;
    const size_t oHdb1 = oHdb0 + (size_t)2 * NB * HD * 2;
    const size_t oDyn  = oHdb1 + (size_t)2 * NB * HD * 2;

    int Tc = 4;
    const int cand[6] = {128, 64, 32, 16, 8, 4};
    for (int i = 0; i < 6; i++) {
        size_t need = oDyn + (size_t)cand[i] * NB * (CIN + G3 + 2 * HD) * 2;
        if (need <= ws_size) { Tc = cand[i]; break; }
    }
    const size_t oXC  = oDyn;
    const size_t oGI  = oXC + (size_t)Tc * NB * CIN * 2;
    const size_t oY0c = oGI + (size_t)Tc * NB * G3 * 2;
    const size_t oY1c = oY0c + (size_t)Tc * NB * HD * 2;

    unsigned*       FDT  = (unsigned*)(ws + oFlag);
    unsigned*       DFLG = (unsigned*)(ws + oFlag + 64);
    float*          KEEP = (float*)(ws + oKeep);
    unsigned*       CTR  = (unsigned*)(ws + oCtr);
    unsigned short* WC   = (unsigned short*)(ws + oWC);
    unsigned short* HDB0 = (unsigned short*)(ws + oHdb0);
    unsigned short* HDB1 = (unsigned short*)(ws + oHdb1);
    unsigned short* XC   = (unsigned short*)(ws + oXC);
    unsigned short* GIb  = (unsigned short*)(ws + oGI);
    unsigned short* Y0c  = (unsigned short*)(ws + oY0c);
    unsigned short* Y1c  = (unsigned short*)(ws + oY1c);

    unsigned short* MEMc = WC + wcOff[0] / 2;
    unsigned short* WIH0 = WC + wcOff[1] / 2;
    unsigned short* WHH0 = WC + wcOff[2] / 2;
    unsigned short* BIH0 = WC + wcOff[3] / 2;
    unsigned short* BHH0 = WC + wcOff[4] / 2;
    unsigned short* WIH1 = WC + wcOff[5] / 2;
    unsigned short* WHH1 = WC + wcOff[6] / 2;
    unsigned short* BIH1 = WC + wcOff[7] / 2;
    unsigned short* BHH1 = WC + wcOff[8] / 2;
    unsigned short* WPc  = WC + wcOff[9] / 2;
    unsigned short* BPc  = WC + wcOff[10] / 2;

    hipMemsetAsync(ws + oCtr, 0, (size_t)4 * 1024 * 1024, stream);
    detect_fdt<<<1, 256, 0, stream>>>((const unsigned short*)x, 4096, FDT);
    detect_done<<<1, 256, 0, stream>>>((const unsigned char*)done, in_sizes[2], DFLG);
    expand_done<<<(LSEQ * NB + 255) / 256, 256, 0, stream>>>(done, DFLG, KEEP, LSEQ * NB);

    for (int i = 0; i < 11; i++) {
        int blocks = (int)((fn[i] + 1023) / 1024);
        if (blocks > 2048) blocks = 2048;
        cast_bf16<<<blocks, 256, 0, stream>>>(fsrc[i], 0, WC + wcOff[i] / 2, fn[i], FDT);
    }

    size_t ctrWords = 0;
    const size_t ctrStep = (size_t)(Tc + 1) * 16 * 32;
    for (int t0 = 0; t0 < LSEQ; t0 += Tc) {
        const long xcN = (long)Tc * NB * CIN;
        cast_bf16<<<2048, 256, 0, stream>>>(x, (long)t0 * NB * CIN, XC, xcN, FDT);
        gemm_nt<<<dim3(G3 / 128, Tc * NB / 128), 256, 0, stream>>>(
            XC, WIH0, BIH0, GIb, nullptr, nullptr, Tc * NB, G3, CIN);
        gru_rec<<<256, 256, 0, stream>>>(GIb, WHH0, BHH0, KEEP, MEMc, HDB0,
                                         Y0c, hnB, hnF, FDT, t0, Tc, 0, CTR + ctrWords);
        ctrWords += ctrStep;
        gemm_nt<<<dim3(G3 / 128, Tc * NB / 128), 256, 0, stream>>>(
            Y0c, WIH1, BIH1, GIb, nullptr, nullptr, Tc * NB, G3, HD);
        gru_rec<<<256, 256, 0, stream>>>(GIb, WHH1, BHH1, KEEP, MEMc, HDB1,
                                         Y1c, hnB, hnF, FDT, t0, Tc, HD, CTR + ctrWords);
        ctrWords += ctrStep;
        gemm_nt<<<dim3(NOUT / 128, Tc * NB / 128), 256, 0, stream>>>(
            Y1c, WPc, BPc, outB + (size_t)t0 * NB * NOUT,
            outF + (size_t)t0 * NB * NOUT, FDT, Tc * NB, NOUT, HD);
    }
}